// Round 4
// baseline (303.477 us; speedup 1.0000x reference)
//
#include <hip/hip_runtime.h>
#include <hip/hip_bf16.h>
#include <math.h>

#define DEV __device__ __forceinline__

typedef __bf16 bf16;
typedef __bf16 bf16x8 __attribute__((ext_vector_type(8)));
typedef float f32x4 __attribute__((ext_vector_type(4)));

DEV f32x4 zero4() { f32x4 z; z[0]=0.f; z[1]=0.f; z[2]=0.f; z[3]=0.f; return z; }

DEV void gload_lds16(const bf16* g, bf16* l) {
    __builtin_amdgcn_global_load_lds(
        (const __attribute__((address_space(1))) void*)g,
        (__attribute__((address_space(3))) void*)l, 16, 0, 0);
}

// ---------------------------------------------------------------------------
// Geometry: B=2, C=192, T=8, H=56, W=56; window (2,7,7) N=98; shift (1,3,3)
// windows: 4*8*8=256 per batch, B_=512; tokens M = 50176
// ---------------------------------------------------------------------------

// K0: transpose weights to (N,K) k-contiguous bf16
__global__ __launch_bounds__(256) void prep_w_k(
    const float* __restrict__ qw, const float* __restrict__ pw,
    const float* __restrict__ f1, const float* __restrict__ f2,
    bf16* __restrict__ qwt, bf16* __restrict__ pwt,
    bf16* __restrict__ f1t, bf16* __restrict__ f2t)
{
    int i = blockIdx.x * 256 + threadIdx.x;
    if (i < 576*192) { int n = i / 192, k = i % 192; qwt[i] = (bf16)qw[(size_t)k*576 + n]; }
    if (i < 192*192) { int n = i / 192, k = i % 192; pwt[i] = (bf16)pw[(size_t)k*192 + n]; }
    if (i < 768*192) { int n = i / 192, k = i % 192; f1t[i] = (bf16)f1[(size_t)k*768 + n]; }
    if (i < 192*768) { int n = i / 768, k = i % 768; f2t[i] = (bf16)f2[(size_t)k*192 + n]; }
}

// K0b: bias table biasT[head][nq][nk_pad=112], nk>=98 -> -1e30.
__global__ __launch_bounds__(256) void prep_bias_k(
    const float* __restrict__ rpb, float* __restrict__ biasT)
{
    int i = blockIdx.x * 256 + threadIdx.x;
    if (i >= 6*98*112) return;
    int nk = i % 112; int t = i / 112; int nq = t % 98; int h = t / 98;
    float v;
    if (nk < 98) {
        int t1 = nq/49, r1 = nq%49, h1 = r1/7, w1 = r1%7;
        int t2 = nk/49, r2 = nk%49, h2 = r2/7, w2 = r2%7;
        int idx = (t1 - t2 + 1)*169 + (h1 - h2 + 6)*13 + (w1 - w2 + 6);
        v = rpb[idx*6 + h];
    } else {
        v = -1e30f;
    }
    biasT[i] = v;
}

// K1: LN1 + cyclic shift + window partition. grid = B*T*H = 896.
__global__ __launch_bounds__(256) void ln1_window_k(
    const float* __restrict__ x, const float* __restrict__ g,
    const float* __restrict__ bta, bf16* __restrict__ xw)
{
    __shared__ float tile[56*193];
    __shared__ float mu[56], rs[56];
    int blk = blockIdx.x;
    int bb = blk / 448; int r = blk % 448; int ts = r / 56; int hs = r % 56;
    int t = (ts + 1) & 7;
    int h = hs + 3; if (h >= 56) h -= 56;
    int tid = threadIdx.x;
    const float* xs = x + ((size_t)bb*1536 + t)*3136 + h*56;
    for (int e = tid; e < 192*56; e += 256) {
        int c = e / 56, w = e % 56;
        int wsp = w - 3; if (wsp < 0) wsp += 56;
        tile[wsp*193 + c] = xs[(size_t)c*25088 + w];
    }
    __syncthreads();
    if (tid < 56) {
        float s = 0.f, s2 = 0.f;
        for (int c = 0; c < 192; c++) { float v = tile[tid*193 + c]; s += v; s2 += v*v; }
        float m = s * (1.0f/192.0f);
        float var = s2 * (1.0f/192.0f) - m*m;
        mu[tid] = m; rs[tid] = rsqrtf(var + 1e-5f);
    }
    __syncthreads();
    int tb = ts >> 1, wt = ts & 1;
    int hb = hs / 7, wh = hs % 7;
    for (int e = tid; e < 56*192; e += 256) {
        int wpos = e / 192, c = e % 192;
        float v = (tile[wpos*193 + c] - mu[wpos]) * rs[wpos] * g[c] + bta[c];
        int wb = wpos / 7, ww = wpos % 7;
        int widx = bb*256 + tb*64 + hb*8 + wb;
        int n = wt*49 + wh*7 + ww;
        xw[((size_t)widx*98 + n)*192 + c] = (bf16)v;
    }
}

// Generic bf16 MFMA GEMM: C(M,NT) = A(M,KT) @ BT(NT,KT)^T + bias, M=50176.
// BM=128 BN=64 BK=64. Staging via global_load_lds (linear LDS dest,
// source-swizzled global addr; fragment reads use the same XOR involution).
template<int KT, int NT, int EPI>
__global__ __launch_bounds__(256) void gemm_k(
    const bf16* __restrict__ A, const bf16* __restrict__ BT,
    const float* __restrict__ bias, const float* __restrict__ resid,
    void* __restrict__ outp)
{
    __shared__ bf16 la[128*64];
    __shared__ bf16 lb[64*64];
    constexpr int NTILES = NT / 64;
    int bid = blockIdx.x;
    int m0 = (bid / NTILES) * 128;
    int n0 = (bid % NTILES) * 64;
    int tid = threadIdx.x;
    int lane = tid & 63;
    int wv = tid >> 6;
    int wr = wv >> 1, wc = wv & 1;
    int l15 = lane & 15, lg = lane >> 4;

    f32x4 acc[4][2];
    #pragma unroll
    for (int i = 0; i < 4; i++)
        #pragma unroll
        for (int j = 0; j < 2; j++) acc[i][j] = zero4();

    for (int kb = 0; kb < KT; kb += 64) {
        // A: 1024 16B-chunks, 4 rounds x 4 waves x 64 lanes
        #pragma unroll
        for (int t = 0; t < 4; t++) {
            int e = t*256 + wv*64 + lane;
            int row = e >> 3, ck = e & 7;
            gload_lds16(&A[(size_t)(m0 + row)*KT + kb + ((ck ^ (row & 7)) << 3)],
                        &la[(t*256 + wv*64) * 8]);
        }
        // B: 512 chunks, 2 rounds
        #pragma unroll
        for (int t = 0; t < 2; t++) {
            int e = t*256 + wv*64 + lane;
            int row = e >> 3, ck = e & 7;
            gload_lds16(&BT[(size_t)(n0 + row)*KT + kb + ((ck ^ (row & 7)) << 3)],
                        &lb[(t*256 + wv*64) * 8]);
        }
        __syncthreads();
        #pragma unroll
        for (int ks = 0; ks < 64; ks += 32) {
            int lc = (ks >> 3) + lg;
            bf16x8 af[4], bfr[2];
            #pragma unroll
            for (int i = 0; i < 4; i++) {
                int ri = wr*64 + i*16 + l15;
                af[i] = *(const bf16x8*)&la[ri*64 + ((lc ^ (ri & 7)) << 3)];
            }
            #pragma unroll
            for (int j = 0; j < 2; j++) {
                int rj = wc*32 + j*16 + l15;
                bfr[j] = *(const bf16x8*)&lb[rj*64 + ((lc ^ (rj & 7)) << 3)];
            }
            #pragma unroll
            for (int i = 0; i < 4; i++)
                #pragma unroll
                for (int j = 0; j < 2; j++)
                    acc[i][j] = __builtin_amdgcn_mfma_f32_16x16x32_bf16(af[i], bfr[j], acc[i][j], 0, 0, 0);
        }
        __syncthreads();
    }

    #pragma unroll
    for (int i = 0; i < 4; i++) {
        #pragma unroll
        for (int j = 0; j < 2; j++) {
            #pragma unroll
            for (int r = 0; r < 4; r++) {
                int row = m0 + wr*64 + i*16 + lg*4 + r;
                int col = n0 + wc*32 + j*16 + l15;
                float v = acc[i][j][r] + bias[col];
                size_t oidx = (size_t)row * NT + col;
                if constexpr (EPI == 0) {
                    ((bf16*)outp)[oidx] = (bf16)v;
                } else if constexpr (EPI == 1) {
                    ((float*)outp)[oidx] = v;
                } else if constexpr (EPI == 2) {
                    float gl = 0.5f * v * (1.0f + erff(v * 0.70710678118654752f));
                    ((bf16*)outp)[oidx] = (bf16)gl;
                } else {
                    ((float*)outp)[oidx] = v + resid[oidx];
                }
            }
        }
    }
}

// K3: attention, one block per WINDOW. grid 512, block 384 (6 waves).
// Wave wv owns head wv: 7 row-tiles per wave. K fragments hoisted to
// registers (no K LDS). LDS: VT[192][128] XOR-swizzled (49.2KB) +
// per-wave P [16][136] (25.5KB) = 73.5KB -> 2 blocks/CU.
__global__ __launch_bounds__(384) void attn_k(
    const bf16* __restrict__ qkv, const float* __restrict__ biasT,
    const float* __restrict__ maskm, bf16* __restrict__ aout)
{
    __shared__ bf16 VT[192*128];     // [d][key^((d&7)<<3)], keys>=98 zero
    __shared__ bf16 Pl[6*16*136];
    int b_ = blockIdx.x;
    int tid = threadIdx.x, lane = tid & 63, wv = tid >> 6;
    int l15 = lane & 15, lg = (lane >> 4) & 3;
    int wib = b_ & 255;
    int head = wv;
    const bf16* base = qkv + (size_t)b_*98*576;

    // ---- phase 0: zero VT fully + P pad cols ----
    {
        unsigned int* vz = (unsigned int*)VT;
        for (int e = tid; e < (192*128)/2; e += 384) vz[e] = 0u;
        unsigned int* pz = (unsigned int*)Pl;      // P cols 112..127
        for (int e = tid; e < 768; e += 384) {
            int w2 = e >> 7, rem = e & 127;
            int row = rem >> 3, cp = rem & 7;
            pz[(w2*16 + row)*68 + 56 + cp] = 0u;
        }
    }
    __syncthreads();
    // ---- phase 1: stage V transposed, swizzle phys_col = key ^ (jj<<3) ----
    for (int i = tid; i < 2352; i += 384) {
        int n = i / 24, ck = i % 24;
        bf16x8 v8 = *(const bf16x8*)&base[(size_t)n*576 + 384 + ck*8];
        #pragma unroll
        for (int jj = 0; jj < 8; jj++)
            VT[(ck*8 + jj)*128 + (n ^ (jj << 3))] = v8[jj];
    }
    __syncthreads();

    // ---- K fragments into registers (reused across 7 row-tiles) ----
    bf16x8 kfr[7];
    #pragma unroll
    for (int j = 0; j < 7; j++) {
        int krow = j*16 + l15; if (krow > 97) krow = 97;   // NaN guard
        kfr[j] = *(const bf16x8*)&base[(size_t)krow*576 + 192 + head*32 + lg*8];
    }

    const float scale = 0.17677669529663687f;   // 32^-0.5
    bf16* Pw = Pl + wv*16*136;

    #pragma unroll 1
    for (int rt = 0; rt < 7; rt++) {
        int qrow = rt*16 + l15; if (qrow > 97) qrow = 97;
        bf16x8 qf = *(const bf16x8*)&base[(size_t)qrow*576 + head*32 + lg*8];
        // ---- S = Q K^T ----
        f32x4 sacc[7];
        #pragma unroll
        for (int j = 0; j < 7; j++) sacc[j] = zero4();
        #pragma unroll
        for (int j = 0; j < 7; j++)
            sacc[j] = __builtin_amdgcn_mfma_f32_16x16x32_bf16(qf, kfr[j], sacc[j], 0, 0, 0);
        // ---- softmax (bias table has -1e30 in pad cols) ----
        #pragma unroll
        for (int r = 0; r < 4; r++) {
            int nq = rt*16 + lg*4 + r;
            int nqc = nq > 97 ? 97 : nq;
            const float* bb = biasT + (head*98 + nqc)*112;
            const float* mm = maskm + ((size_t)wib*98 + nqc)*98;
            float sv[7];
            float m = -1e30f;
            #pragma unroll
            for (int j = 0; j < 7; j++) {
                int nk = j*16 + l15;
                float v = sacc[j][r]*scale + bb[nk];
                if (nk < 98) v += mm[nk];
                sv[j] = v; m = fmaxf(m, v);
            }
            #pragma unroll
            for (int d = 1; d < 16; d <<= 1) m = fmaxf(m, __shfl_xor(m, d));
            float sum = 0.f;
            #pragma unroll
            for (int j = 0; j < 7; j++) { sv[j] = __expf(sv[j] - m); sum += sv[j]; }
            #pragma unroll
            for (int d = 1; d < 16; d <<= 1) sum += __shfl_xor(sum, d);
            float inv = 1.0f / sum;
            #pragma unroll
            for (int j = 0; j < 7; j++)
                Pw[(lg*4 + r)*136 + j*16 + l15] = (bf16)(sv[j]*inv);
        }
        // ---- O = P V ----
        #pragma unroll
        for (int dt = 0; dt < 2; dt++) {
            int drow = head*32 + dt*16 + l15;
            int xr = (drow & 7) << 3;
            f32x4 oacc = zero4();
            #pragma unroll
            for (int kc = 0; kc < 4; kc++) {
                bf16x8 pf = *(const bf16x8*)&Pw[l15*136 + kc*32 + lg*8];
                bf16x8 vf = *(const bf16x8*)&VT[drow*128 + ((kc*32 + lg*8) ^ xr)];
                oacc = __builtin_amdgcn_mfma_f32_16x16x32_bf16(pf, vf, oacc, 0, 0, 0);
            }
            #pragma unroll
            for (int r = 0; r < 4; r++) {
                int row = rt*16 + lg*4 + r;
                if (row < 98)
                    aout[((size_t)b_*98 + row)*192 + head*32 + dt*16 + l15] = (bf16)oacc[r];
            }
        }
    }
}

// K5: window reverse + roll-back + residual(x) + LN2. grid 896.
__global__ __launch_bounds__(256) void rev_res_ln2_k(
    const float* __restrict__ x, const float* __restrict__ pw,
    const float* __restrict__ g2, const float* __restrict__ b2,
    float* __restrict__ x1, bf16* __restrict__ xn2)
{
    __shared__ float tile[56*193];
    __shared__ float mu[56], rs[56];
    int blk = blockIdx.x;
    int bb = blk / 448; int r = blk % 448; int t = r / 56; int h = r % 56;
    int ts = (t + 7) & 7;
    int hs = h - 3; if (hs < 0) hs += 56;
    int tid = threadIdx.x;
    const float* xs = x + ((size_t)bb*1536 + t)*3136 + h*56;
    for (int e = tid; e < 192*56; e += 256) {
        int c = e / 56, w = e % 56;
        tile[w*193 + c] = xs[(size_t)c*25088 + w];
    }
    __syncthreads();
    int tb = ts >> 1, wt = ts & 1, hb = hs / 7, wh = hs % 7;
    for (int e = tid; e < 56*192; e += 256) {
        int w = e / 192, c = e % 192;
        int wsp = w - 3; if (wsp < 0) wsp += 56;
        int wb = wsp / 7, ww = wsp % 7;
        size_t tok = (size_t)(bb*256 + tb*64 + hb*8 + wb)*98 + wt*49 + wh*7 + ww;
        tile[w*193 + c] += pw[tok*192 + c];
    }
    __syncthreads();
    if (tid < 56) {
        float s = 0.f, s2 = 0.f;
        for (int c = 0; c < 192; c++) { float v = tile[tid*193 + c]; s += v; s2 += v*v; }
        float m = s * (1.0f/192.0f);
        float var = s2 * (1.0f/192.0f) - m*m;
        mu[tid] = m; rs[tid] = rsqrtf(var + 1e-5f);
    }
    __syncthreads();
    size_t tok0 = ((size_t)(bb*8 + t)*56 + h)*56;
    for (int e = tid; e < 56*192; e += 256) {
        int w = e / 192, c = e % 192;
        float v = tile[w*193 + c];
        x1[(tok0 + w)*192 + c] = v;
        xn2[(tok0 + w)*192 + c] = (bf16)((v - mu[w]) * rs[w] * g2[c] + b2[c]);
    }
}

// K8: channel-last -> channel-first transpose of final x2. grid 896.
__global__ __launch_bounds__(256) void transpose_out_k(
    const float* __restrict__ xin, float* __restrict__ out)
{
    __shared__ float tile[192*57];
    int blk = blockIdx.x;
    int bb = blk / 448; int r = blk % 448; int t = r / 56; int h = r % 56;
    int tid = threadIdx.x;
    const float* rowp = xin + ((size_t)(bb*8 + t)*56 + h)*56*192;
    for (int e = tid; e < 56*192; e += 256) {
        int w = e / 192, c = e % 192;
        tile[c*57 + w] = rowp[e];
    }
    __syncthreads();
    float* op = out + (size_t)bb*192*25088 + (size_t)t*3136 + h*56;
    for (int e = tid; e < 192*56; e += 256) {
        int c = e / 56, w = e % 56;
        op[(size_t)c*25088 + w] = tile[c*57 + w];
    }
}

// ---------------------------------------------------------------------------
extern "C" void kernel_launch(void* const* d_in, const int* in_sizes, int n_in,
                              void* d_out, int out_size, void* d_ws, size_t ws_size,
                              hipStream_t stream)
{
    const float* x     = (const float*)d_in[0];
    const float* maskm = (const float*)d_in[1];
    const float* n1g   = (const float*)d_in[2];
    const float* n1b   = (const float*)d_in[3];
    const float* qkvw  = (const float*)d_in[4];
    const float* qkvb  = (const float*)d_in[5];
    const float* projw = (const float*)d_in[6];
    const float* projb = (const float*)d_in[7];
    const float* rpb   = (const float*)d_in[8];
    const float* n2g   = (const float*)d_in[9];
    const float* n2b   = (const float*)d_in[10];
    const float* f1w   = (const float*)d_in[11];
    const float* f1b   = (const float*)d_in[12];
    const float* f2w   = (const float*)d_in[13];
    const float* f2b   = (const float*)d_in[14];

    char* ws = (char*)d_ws;
    // weights (transposed bf16) + bias table
    bf16*  qkv_wt  = (bf16*)(ws + 0);          // 221184
    bf16*  proj_wt = (bf16*)(ws + 221184);     // 73728
    bf16*  fc1_wt  = (bf16*)(ws + 294912);     // 294912
    bf16*  fc2_wt  = (bf16*)(ws + 589824);     // 294912
    float* biasT   = (float*)(ws + 884736);    // 263424
    // region A: xw (bf16, 19.27MB) -> reused as attn_out
    bf16* xw   = (bf16*)(ws + 1179648);
    bf16* aout = xw;
    // region B: qkv (bf16, 57.8MB) -> reused as proj-out f32 -> fc2-out f32
    char* Bp = ws + 1179648 + 19267584;
    bf16*  qkv  = (bf16*)Bp;
    float* pwin = (float*)Bp;
    float* fc2o = (float*)Bp;
    // region C: x1 f32; region D: xn2 bf16; region E: h1 bf16
    char* Cp = Bp + 57802752;
    float* x1  = (float*)Cp;
    bf16*  xn2 = (bf16*)(Cp + 38535168);
    bf16*  h1  = (bf16*)(Cp + 38535168 + 19267584);

    prep_w_k<<<576, 256, 0, stream>>>(qkvw, projw, f1w, f2w, qkv_wt, proj_wt, fc1_wt, fc2_wt);
    prep_bias_k<<<258, 256, 0, stream>>>(rpb, biasT);
    ln1_window_k<<<896, 256, 0, stream>>>(x, n1g, n1b, xw);
    gemm_k<192, 576, 0><<<392*9, 256, 0, stream>>>(xw, qkv_wt, qkvb, nullptr, qkv);
    attn_k<<<512, 384, 0, stream>>>(qkv, biasT, maskm, aout);
    gemm_k<192, 192, 1><<<392*3, 256, 0, stream>>>(aout, proj_wt, projb, nullptr, pwin);
    rev_res_ln2_k<<<896, 256, 0, stream>>>(x, pwin, n2g, n2b, x1, xn2);
    gemm_k<192, 768, 2><<<392*12, 256, 0, stream>>>(xn2, fc1_wt, f1b, nullptr, h1);
    gemm_k<768, 192, 3><<<392*3, 256, 0, stream>>>(h1, fc2_wt, f2b, x1, fc2o);
    transpose_out_k<<<896, 256, 0, stream>>>(fc2o, (float*)d_out);
}

// Round 5
// 285.969 us; speedup vs baseline: 1.0612x; 1.0612x over previous
//
#include <hip/hip_runtime.h>
#include <hip/hip_bf16.h>
#include <math.h>

#define DEV __device__ __forceinline__

typedef __bf16 bf16;
typedef __bf16 bf16x8 __attribute__((ext_vector_type(8)));
typedef float f32x4 __attribute__((ext_vector_type(4)));

DEV f32x4 zero4() { f32x4 z; z[0]=0.f; z[1]=0.f; z[2]=0.f; z[3]=0.f; return z; }

DEV void gload_lds16(const bf16* g, bf16* l) {
    __builtin_amdgcn_global_load_lds(
        (const __attribute__((address_space(1))) void*)g,
        (__attribute__((address_space(3))) void*)l, 16, 0, 0);
}

// ---------------------------------------------------------------------------
// Geometry: B=2, C=192, T=8, H=56, W=56; window (2,7,7) N=98; shift (1,3,3)
// windows: 4*8*8=256 per batch, B_=512; tokens M = 50176
// ---------------------------------------------------------------------------

// K0: transpose weights to (N,K) k-contiguous bf16
__global__ __launch_bounds__(256) void prep_w_k(
    const float* __restrict__ qw, const float* __restrict__ pw,
    const float* __restrict__ f1, const float* __restrict__ f2,
    bf16* __restrict__ qwt, bf16* __restrict__ pwt,
    bf16* __restrict__ f1t, bf16* __restrict__ f2t)
{
    int i = blockIdx.x * 256 + threadIdx.x;
    if (i < 576*192) { int n = i / 192, k = i % 192; qwt[i] = (bf16)qw[(size_t)k*576 + n]; }
    if (i < 192*192) { int n = i / 192, k = i % 192; pwt[i] = (bf16)pw[(size_t)k*192 + n]; }
    if (i < 768*192) { int n = i / 192, k = i % 192; f1t[i] = (bf16)f1[(size_t)k*768 + n]; }
    if (i < 192*768) { int n = i / 768, k = i % 768; f2t[i] = (bf16)f2[(size_t)k*192 + n]; }
}

// K0b: bias table biasT[head][nq][nk_pad=112], nk>=98 -> -1e30.
__global__ __launch_bounds__(256) void prep_bias_k(
    const float* __restrict__ rpb, float* __restrict__ biasT)
{
    int i = blockIdx.x * 256 + threadIdx.x;
    if (i >= 6*98*112) return;
    int nk = i % 112; int t = i / 112; int nq = t % 98; int h = t / 98;
    float v;
    if (nk < 98) {
        int t1 = nq/49, r1 = nq%49, h1 = r1/7, w1 = r1%7;
        int t2 = nk/49, r2 = nk%49, h2 = r2/7, w2 = r2%7;
        int idx = (t1 - t2 + 1)*169 + (h1 - h2 + 6)*13 + (w1 - w2 + 6);
        v = rpb[idx*6 + h];
    } else {
        v = -1e30f;
    }
    biasT[i] = v;
}

// K1: LN1 + cyclic shift + window partition. grid = B*T*H = 896.
__global__ __launch_bounds__(256) void ln1_window_k(
    const float* __restrict__ x, const float* __restrict__ g,
    const float* __restrict__ bta, bf16* __restrict__ xw)
{
    __shared__ float tile[56*193];
    __shared__ float mu[56], rs[56];
    int blk = blockIdx.x;
    int bb = blk / 448; int r = blk % 448; int ts = r / 56; int hs = r % 56;
    int t = (ts + 1) & 7;
    int h = hs + 3; if (h >= 56) h -= 56;
    int tid = threadIdx.x;
    const float* xs = x + ((size_t)bb*1536 + t)*3136 + h*56;
    for (int e = tid; e < 192*56; e += 256) {
        int c = e / 56, w = e % 56;
        int wsp = w - 3; if (wsp < 0) wsp += 56;
        tile[wsp*193 + c] = xs[(size_t)c*25088 + w];
    }
    __syncthreads();
    if (tid < 56) {
        float s = 0.f, s2 = 0.f;
        for (int c = 0; c < 192; c++) { float v = tile[tid*193 + c]; s += v; s2 += v*v; }
        float m = s * (1.0f/192.0f);
        float var = s2 * (1.0f/192.0f) - m*m;
        mu[tid] = m; rs[tid] = rsqrtf(var + 1e-5f);
    }
    __syncthreads();
    int tb = ts >> 1, wt = ts & 1;
    int hb = hs / 7, wh = hs % 7;
    for (int e = tid; e < 56*192; e += 256) {
        int wpos = e / 192, c = e % 192;
        float v = (tile[wpos*193 + c] - mu[wpos]) * rs[wpos] * g[c] + bta[c];
        int wb = wpos / 7, ww = wpos % 7;
        int widx = bb*256 + tb*64 + hb*8 + wb;
        int n = wt*49 + wh*7 + ww;
        xw[((size_t)widx*98 + n)*192 + c] = (bf16)v;
    }
}

// Generic bf16 MFMA GEMM: C(M,NT) = A(M,KT) @ BT(NT,KT)^T + bias, M=50176.
// BM=128 BN=64 BK=64. Staging via global_load_lds (linear LDS dest,
// source-swizzled global addr; fragment reads use the same XOR involution).
template<int KT, int NT, int EPI>
__global__ __launch_bounds__(256) void gemm_k(
    const bf16* __restrict__ A, const bf16* __restrict__ BT,
    const float* __restrict__ bias, const float* __restrict__ resid,
    void* __restrict__ outp)
{
    __shared__ bf16 la[128*64];
    __shared__ bf16 lb[64*64];
    constexpr int NTILES = NT / 64;
    int bid = blockIdx.x;
    int m0 = (bid / NTILES) * 128;
    int n0 = (bid % NTILES) * 64;
    int tid = threadIdx.x;
    int lane = tid & 63;
    int wv = tid >> 6;
    int wr = wv >> 1, wc = wv & 1;
    int l15 = lane & 15, lg = lane >> 4;

    f32x4 acc[4][2];
    #pragma unroll
    for (int i = 0; i < 4; i++)
        #pragma unroll
        for (int j = 0; j < 2; j++) acc[i][j] = zero4();

    for (int kb = 0; kb < KT; kb += 64) {
        #pragma unroll
        for (int t = 0; t < 4; t++) {
            int e = t*256 + wv*64 + lane;
            int row = e >> 3, ck = e & 7;
            gload_lds16(&A[(size_t)(m0 + row)*KT + kb + ((ck ^ (row & 7)) << 3)],
                        &la[(t*256 + wv*64) * 8]);
        }
        #pragma unroll
        for (int t = 0; t < 2; t++) {
            int e = t*256 + wv*64 + lane;
            int row = e >> 3, ck = e & 7;
            gload_lds16(&BT[(size_t)(n0 + row)*KT + kb + ((ck ^ (row & 7)) << 3)],
                        &lb[(t*256 + wv*64) * 8]);
        }
        __syncthreads();
        #pragma unroll
        for (int ks = 0; ks < 64; ks += 32) {
            int lc = (ks >> 3) + lg;
            bf16x8 af[4], bfr[2];
            #pragma unroll
            for (int i = 0; i < 4; i++) {
                int ri = wr*64 + i*16 + l15;
                af[i] = *(const bf16x8*)&la[ri*64 + ((lc ^ (ri & 7)) << 3)];
            }
            #pragma unroll
            for (int j = 0; j < 2; j++) {
                int rj = wc*32 + j*16 + l15;
                bfr[j] = *(const bf16x8*)&lb[rj*64 + ((lc ^ (rj & 7)) << 3)];
            }
            #pragma unroll
            for (int i = 0; i < 4; i++)
                #pragma unroll
                for (int j = 0; j < 2; j++)
                    acc[i][j] = __builtin_amdgcn_mfma_f32_16x16x32_bf16(af[i], bfr[j], acc[i][j], 0, 0, 0);
        }
        __syncthreads();
    }

    #pragma unroll
    for (int i = 0; i < 4; i++) {
        #pragma unroll
        for (int j = 0; j < 2; j++) {
            #pragma unroll
            for (int r = 0; r < 4; r++) {
                int row = m0 + wr*64 + i*16 + lg*4 + r;
                int col = n0 + wc*32 + j*16 + l15;
                float v = acc[i][j][r] + bias[col];
                size_t oidx = (size_t)row * NT + col;
                if constexpr (EPI == 0) {
                    ((bf16*)outp)[oidx] = (bf16)v;
                } else if constexpr (EPI == 1) {
                    ((float*)outp)[oidx] = v;
                } else if constexpr (EPI == 2) {
                    float gl = 0.5f * v * (1.0f + erff(v * 0.70710678118654752f));
                    ((bf16*)outp)[oidx] = (bf16)gl;
                } else {
                    ((float*)outp)[oidx] = v + resid[oidx];
                }
            }
        }
    }
}

// K3: attention, one block per (WINDOW, HEAD). grid 3072, block 128 (2 waves).
// Wave 0 -> row-tiles 0..3, wave 1 -> 4..6. K frags in registers.
// LDS: per-head VT[32][128] swizzled (8KB) + P[2][16][136] (8.5KB) = 16.9KB
// -> ~8 blocks/CU. XCD-aware mapping: all 6 heads of a window + 64
// consecutive windows land on one XCD (qkv/mask/bias L2-resident).
__global__ __launch_bounds__(128) void attn_k(
    const bf16* __restrict__ qkv, const float* __restrict__ biasT,
    const float* __restrict__ maskm, bf16* __restrict__ aout)
{
    __shared__ bf16 VT[32*128];      // [d][key ^ ((d&7)<<3)], keys>=98 zero
    __shared__ bf16 Pl[2*16*136];
    int blk = blockIdx.x;
    int t8 = (blk & 7) * 384 + (blk >> 3);   // XCD-contiguous task id
    int b_ = t8 / 6, head = t8 % 6;
    int tid = threadIdx.x, lane = tid & 63, wv = tid >> 6;
    int l15 = lane & 15, lg = (lane >> 4) & 3;
    int wib = b_ & 255;
    const bf16* base = qkv + (size_t)b_*98*576;

    // ---- phase 0: zero VT fully + P pad cols (112..127) ----
    {
        unsigned int* vz = (unsigned int*)VT;
        for (int e = tid; e < 2048; e += 128) vz[e] = 0u;
        unsigned int* pz = (unsigned int*)Pl;
        for (int e = tid; e < 256; e += 128) {
            int w2 = e >> 7, rem = e & 127;
            int row = rem >> 3, cp = rem & 7;
            pz[(w2*16 + row)*68 + 56 + cp] = 0u;
        }
    }
    __syncthreads();
    // ---- phase 1: stage V^T slice; k varies with lane (conflict-free) ----
    {
        int dq = tid >> 5;               // d-octet 0..3
        int kl = tid & 31;
        const bf16* vbase = base + 384 + head*32 + dq*8;
        #pragma unroll
        for (int kr = 0; kr < 4; kr++) {
            int k = kr*32 + kl;
            if (k < 98) {
                bf16x8 v8 = *(const bf16x8*)&vbase[(size_t)k*576];
                #pragma unroll
                for (int j = 0; j < 8; j++)
                    VT[(dq*8 + j)*128 + (k ^ (j << 3))] = v8[j];
            }
        }
    }
    __syncthreads();

    // ---- K fragments into registers (reused across row-tiles) ----
    bf16x8 kfr[7];
    #pragma unroll
    for (int j = 0; j < 7; j++) {
        int krow = j*16 + l15; if (krow > 97) krow = 97;   // NaN guard
        kfr[j] = *(const bf16x8*)&base[(size_t)krow*576 + 192 + head*32 + lg*8];
    }

    const float scale = 0.17677669529663687f;   // 32^-0.5
    bf16* Pw = Pl + wv*16*136;
    int rt0 = wv ? 4 : 0, rt1 = wv ? 7 : 4;

    #pragma unroll 1
    for (int rt = rt0; rt < rt1; rt++) {
        int qrow = rt*16 + l15; if (qrow > 97) qrow = 97;
        bf16x8 qf = *(const bf16x8*)&base[(size_t)qrow*576 + head*32 + lg*8];
        // ---- S = Q K^T ----
        f32x4 sacc[7];
        #pragma unroll
        for (int j = 0; j < 7; j++) sacc[j] = zero4();
        #pragma unroll
        for (int j = 0; j < 7; j++)
            sacc[j] = __builtin_amdgcn_mfma_f32_16x16x32_bf16(qf, kfr[j], sacc[j], 0, 0, 0);
        // ---- softmax (bias table has -1e30 in pad cols) ----
        #pragma unroll
        for (int r = 0; r < 4; r++) {
            int nq = rt*16 + lg*4 + r;
            int nqc = nq > 97 ? 97 : nq;
            const float* bb = biasT + (head*98 + nqc)*112;
            const float* mm = maskm + ((size_t)wib*98 + nqc)*98;
            float sv[7];
            float m = -1e30f;
            #pragma unroll
            for (int j = 0; j < 7; j++) {
                int nk = j*16 + l15;
                float v = sacc[j][r]*scale + bb[nk];
                if (nk < 98) v += mm[nk];
                sv[j] = v; m = fmaxf(m, v);
            }
            #pragma unroll
            for (int d = 1; d < 16; d <<= 1) m = fmaxf(m, __shfl_xor(m, d));
            float sum = 0.f;
            #pragma unroll
            for (int j = 0; j < 7; j++) { sv[j] = __expf(sv[j] - m); sum += sv[j]; }
            #pragma unroll
            for (int d = 1; d < 16; d <<= 1) sum += __shfl_xor(sum, d);
            float inv = 1.0f / sum;
            #pragma unroll
            for (int j = 0; j < 7; j++)
                Pw[(lg*4 + r)*136 + j*16 + l15] = (bf16)(sv[j]*inv);
        }
        // ---- O = P V ----
        #pragma unroll
        for (int dt = 0; dt < 2; dt++) {
            int dl = dt*16 + l15;                 // local d within head slice
            int xr = (dl & 7) << 3;
            f32x4 oacc = zero4();
            #pragma unroll
            for (int kc = 0; kc < 4; kc++) {
                bf16x8 pf = *(const bf16x8*)&Pw[l15*136 + kc*32 + lg*8];
                bf16x8 vf = *(const bf16x8*)&VT[dl*128 + ((kc*32 + lg*8) ^ xr)];
                oacc = __builtin_amdgcn_mfma_f32_16x16x32_bf16(pf, vf, oacc, 0, 0, 0);
            }
            #pragma unroll
            for (int r = 0; r < 4; r++) {
                int row = rt*16 + lg*4 + r;
                if (row < 98)
                    aout[((size_t)b_*98 + row)*192 + head*32 + dt*16 + l15] = (bf16)oacc[r];
            }
        }
    }
}

// K5: window reverse + roll-back + residual(x) + LN2. grid 896.
__global__ __launch_bounds__(256) void rev_res_ln2_k(
    const float* __restrict__ x, const float* __restrict__ pw,
    const float* __restrict__ g2, const float* __restrict__ b2,
    float* __restrict__ x1, bf16* __restrict__ xn2)
{
    __shared__ float tile[56*193];
    __shared__ float mu[56], rs[56];
    int blk = blockIdx.x;
    int bb = blk / 448; int r = blk % 448; int t = r / 56; int h = r % 56;
    int ts = (t + 7) & 7;
    int hs = h - 3; if (hs < 0) hs += 56;
    int tid = threadIdx.x;
    const float* xs = x + ((size_t)bb*1536 + t)*3136 + h*56;
    for (int e = tid; e < 192*56; e += 256) {
        int c = e / 56, w = e % 56;
        tile[w*193 + c] = xs[(size_t)c*25088 + w];
    }
    __syncthreads();
    int tb = ts >> 1, wt = ts & 1, hb = hs / 7, wh = hs % 7;
    for (int e = tid; e < 56*192; e += 256) {
        int w = e / 192, c = e % 192;
        int wsp = w - 3; if (wsp < 0) wsp += 56;
        int wb = wsp / 7, ww = wsp % 7;
        size_t tok = (size_t)(bb*256 + tb*64 + hb*8 + wb)*98 + wt*49 + wh*7 + ww;
        tile[w*193 + c] += pw[tok*192 + c];
    }
    __syncthreads();
    if (tid < 56) {
        float s = 0.f, s2 = 0.f;
        for (int c = 0; c < 192; c++) { float v = tile[tid*193 + c]; s += v; s2 += v*v; }
        float m = s * (1.0f/192.0f);
        float var = s2 * (1.0f/192.0f) - m*m;
        mu[tid] = m; rs[tid] = rsqrtf(var + 1e-5f);
    }
    __syncthreads();
    size_t tok0 = ((size_t)(bb*8 + t)*56 + h)*56;
    for (int e = tid; e < 56*192; e += 256) {
        int w = e / 192, c = e % 192;
        float v = tile[w*193 + c];
        x1[(tok0 + w)*192 + c] = v;
        xn2[(tok0 + w)*192 + c] = (bf16)((v - mu[w]) * rs[w] * g2[c] + b2[c]);
    }
}

// K8: channel-last -> channel-first transpose of final x2. grid 896.
__global__ __launch_bounds__(256) void transpose_out_k(
    const float* __restrict__ xin, float* __restrict__ out)
{
    __shared__ float tile[192*57];
    int blk = blockIdx.x;
    int bb = blk / 448; int r = blk % 448; int t = r / 56; int h = r % 56;
    int tid = threadIdx.x;
    const float* rowp = xin + ((size_t)(bb*8 + t)*56 + h)*56*192;
    for (int e = tid; e < 56*192; e += 256) {
        int w = e / 192, c = e % 192;
        tile[c*57 + w] = rowp[e];
    }
    __syncthreads();
    float* op = out + (size_t)bb*192*25088 + (size_t)t*3136 + h*56;
    for (int e = tid; e < 192*56; e += 256) {
        int c = e / 56, w = e % 56;
        op[(size_t)c*25088 + w] = tile[c*57 + w];
    }
}

// ---------------------------------------------------------------------------
extern "C" void kernel_launch(void* const* d_in, const int* in_sizes, int n_in,
                              void* d_out, int out_size, void* d_ws, size_t ws_size,
                              hipStream_t stream)
{
    const float* x     = (const float*)d_in[0];
    const float* maskm = (const float*)d_in[1];
    const float* n1g   = (const float*)d_in[2];
    const float* n1b   = (const float*)d_in[3];
    const float* qkvw  = (const float*)d_in[4];
    const float* qkvb  = (const float*)d_in[5];
    const float* projw = (const float*)d_in[6];
    const float* projb = (const float*)d_in[7];
    const float* rpb   = (const float*)d_in[8];
    const float* n2g   = (const float*)d_in[9];
    const float* n2b   = (const float*)d_in[10];
    const float* f1w   = (const float*)d_in[11];
    const float* f1b   = (const float*)d_in[12];
    const float* f2w   = (const float*)d_in[13];
    const float* f2b   = (const float*)d_in[14];

    char* ws = (char*)d_ws;
    // weights (transposed bf16) + bias table
    bf16*  qkv_wt  = (bf16*)(ws + 0);          // 221184
    bf16*  proj_wt = (bf16*)(ws + 221184);     // 73728
    bf16*  fc1_wt  = (bf16*)(ws + 294912);     // 294912
    bf16*  fc2_wt  = (bf16*)(ws + 589824);     // 294912
    float* biasT   = (float*)(ws + 884736);    // 263424
    // region A: xw (bf16, 19.27MB) -> reused as attn_out
    bf16* xw   = (bf16*)(ws + 1179648);
    bf16* aout = xw;
    // region B: qkv (bf16, 57.8MB) -> reused as proj-out f32 -> fc2-out f32
    char* Bp = ws + 1179648 + 19267584;
    bf16*  qkv  = (bf16*)Bp;
    float* pwin = (float*)Bp;
    float* fc2o = (float*)Bp;
    // region C: x1 f32; region D: xn2 bf16; region E: h1 bf16
    char* Cp = Bp + 57802752;
    float* x1  = (float*)Cp;
    bf16*  xn2 = (bf16*)(Cp + 38535168);
    bf16*  h1  = (bf16*)(Cp + 38535168 + 19267584);

    prep_w_k<<<576, 256, 0, stream>>>(qkvw, projw, f1w, f2w, qkv_wt, proj_wt, fc1_wt, fc2_wt);
    prep_bias_k<<<258, 256, 0, stream>>>(rpb, biasT);
    ln1_window_k<<<896, 256, 0, stream>>>(x, n1g, n1b, xw);
    gemm_k<192, 576, 0><<<392*9, 256, 0, stream>>>(xw, qkv_wt, qkvb, nullptr, qkv);
    attn_k<<<3072, 128, 0, stream>>>(qkv, biasT, maskm, aout);
    gemm_k<192, 192, 1><<<392*3, 256, 0, stream>>>(aout, proj_wt, projb, nullptr, pwin);
    rev_res_ln2_k<<<896, 256, 0, stream>>>(x, pwin, n2g, n2b, x1, xn2);
    gemm_k<192, 768, 2><<<392*12, 256, 0, stream>>>(xn2, fc1_wt, f1b, nullptr, h1);
    gemm_k<768, 192, 3><<<392*3, 256, 0, stream>>>(h1, fc2_wt, f2b, x1, fc2o);
    transpose_out_k<<<896, 256, 0, stream>>>(fc2o, (float*)d_out);
}

// Round 6
// 277.414 us; speedup vs baseline: 1.0939x; 1.0308x over previous
//
#include <hip/hip_runtime.h>
#include <hip/hip_bf16.h>
#include <math.h>

#define DEV __device__ __forceinline__

typedef __bf16 bf16;
typedef __bf16 bf16x8 __attribute__((ext_vector_type(8)));
typedef float f32x4 __attribute__((ext_vector_type(4)));

DEV f32x4 zero4() { f32x4 z; z[0]=0.f; z[1]=0.f; z[2]=0.f; z[3]=0.f; return z; }

DEV void gload_lds16(const bf16* g, bf16* l) {
    __builtin_amdgcn_global_load_lds(
        (const __attribute__((address_space(1))) void*)g,
        (__attribute__((address_space(3))) void*)l, 16, 0, 0);
}

// ---------------------------------------------------------------------------
// Geometry: B=2, C=192, T=8, H=56, W=56; window (2,7,7) N=98; shift (1,3,3)
// windows: 4*8*8=256 per batch, B_=512; tokens M = 50176
// ---------------------------------------------------------------------------

// K0: transpose weights to (N,K) k-contiguous bf16
__global__ __launch_bounds__(256) void prep_w_k(
    const float* __restrict__ qw, const float* __restrict__ pw,
    const float* __restrict__ f1, const float* __restrict__ f2,
    bf16* __restrict__ qwt, bf16* __restrict__ pwt,
    bf16* __restrict__ f1t, bf16* __restrict__ f2t)
{
    int i = blockIdx.x * 256 + threadIdx.x;
    if (i < 576*192) { int n = i / 192, k = i % 192; qwt[i] = (bf16)qw[(size_t)k*576 + n]; }
    if (i < 192*192) { int n = i / 192, k = i % 192; pwt[i] = (bf16)pw[(size_t)k*192 + n]; }
    if (i < 768*192) { int n = i / 192, k = i % 192; f1t[i] = (bf16)f1[(size_t)k*768 + n]; }
    if (i < 192*768) { int n = i / 768, k = i % 768; f2t[i] = (bf16)f2[(size_t)k*192 + n]; }
}

// K0b: bias table biasT[head][nq][nk_pad=112], nk>=98 -> -1e30.
__global__ __launch_bounds__(256) void prep_bias_k(
    const float* __restrict__ rpb, float* __restrict__ biasT)
{
    int i = blockIdx.x * 256 + threadIdx.x;
    if (i >= 6*98*112) return;
    int nk = i % 112; int t = i / 112; int nq = t % 98; int h = t / 98;
    float v;
    if (nk < 98) {
        int t1 = nq/49, r1 = nq%49, h1 = r1/7, w1 = r1%7;
        int t2 = nk/49, r2 = nk%49, h2 = r2/7, w2 = r2%7;
        int idx = (t1 - t2 + 1)*169 + (h1 - h2 + 6)*13 + (w1 - w2 + 6);
        v = rpb[idx*6 + h];
    } else {
        v = -1e30f;
    }
    biasT[i] = v;
}

// K1: LN1 + cyclic shift + window partition. grid = B*T*H = 896.
__global__ __launch_bounds__(256) void ln1_window_k(
    const float* __restrict__ x, const float* __restrict__ g,
    const float* __restrict__ bta, bf16* __restrict__ xw)
{
    __shared__ float tile[56*193];
    __shared__ float mu[56], rs[56];
    int blk = blockIdx.x;
    int bb = blk / 448; int r = blk % 448; int ts = r / 56; int hs = r % 56;
    int t = (ts + 1) & 7;
    int h = hs + 3; if (h >= 56) h -= 56;
    int tid = threadIdx.x;
    const float* xs = x + ((size_t)bb*1536 + t)*3136 + h*56;
    for (int e = tid; e < 192*56; e += 256) {
        int c = e / 56, w = e % 56;
        int wsp = w - 3; if (wsp < 0) wsp += 56;
        tile[wsp*193 + c] = xs[(size_t)c*25088 + w];
    }
    __syncthreads();
    if (tid < 224) {                       // 4 lanes per row, wave-parallel stats
        int row = tid >> 2, q = tid & 3;
        float s = 0.f, s2 = 0.f;
        for (int c = q*48; c < q*48 + 48; c++) {
            float v = tile[row*193 + c]; s += v; s2 += v*v;
        }
        s  += __shfl_xor(s, 1);  s  += __shfl_xor(s, 2);
        s2 += __shfl_xor(s2, 1); s2 += __shfl_xor(s2, 2);
        if (q == 0) {
            float m = s * (1.0f/192.0f);
            mu[row] = m;
            rs[row] = rsqrtf(s2 * (1.0f/192.0f) - m*m + 1e-5f);
        }
    }
    __syncthreads();
    int tb = ts >> 1, wt = ts & 1;
    int hb = hs / 7, wh = hs % 7;
    for (int e = tid; e < 56*192; e += 256) {
        int wpos = e / 192, c = e % 192;
        float v = (tile[wpos*193 + c] - mu[wpos]) * rs[wpos] * g[c] + bta[c];
        int wb = wpos / 7, ww = wpos % 7;
        int widx = bb*256 + tb*64 + hb*8 + wb;
        int n = wt*49 + wh*7 + ww;
        xw[((size_t)widx*98 + n)*192 + c] = (bf16)v;
    }
}

// Generic bf16 MFMA GEMM: C(M,NT) = A(M,KT) @ BT(NT,KT)^T + bias, M=50176.
// BM=128 BN=64 BK=64, double-buffered LDS (2-phase pipeline): stage(t+1)
// issued before compute(t); __syncthreads' vmcnt(0) drain lands post-compute.
// EPI: 0 bf16; 1 f32; 2 gelu bf16; 4 resid + channel-first transpose -> d_out.
template<int KT, int NT, int EPI>
__global__ __launch_bounds__(256) void gemm_k(
    const bf16* __restrict__ A, const bf16* __restrict__ BT,
    const float* __restrict__ bias, const float* __restrict__ resid,
    void* __restrict__ outp)
{
    __shared__ bf16 la[2][128*64];
    __shared__ bf16 lb[2][64*64];
    constexpr int NTILES = NT / 64;
    constexpr int NK = KT / 64;
    int bid = blockIdx.x;
    int m0 = (bid / NTILES) * 128;
    int n0 = (bid % NTILES) * 64;
    int tid = threadIdx.x;
    int lane = tid & 63;
    int wv = tid >> 6;
    int wr = wv >> 1, wc = wv & 1;
    int l15 = lane & 15, lg = lane >> 4;

    auto stage = [&](int kt, int buf) {
        int kb = kt * 64;
        #pragma unroll
        for (int t = 0; t < 4; t++) {
            int e = t*256 + wv*64 + lane;
            int row = e >> 3, ck = e & 7;
            gload_lds16(&A[(size_t)(m0 + row)*KT + kb + ((ck ^ (row & 7)) << 3)],
                        &la[buf][(t*256 + wv*64) * 8]);
        }
        #pragma unroll
        for (int t = 0; t < 2; t++) {
            int e = t*256 + wv*64 + lane;
            int row = e >> 3, ck = e & 7;
            gload_lds16(&BT[(size_t)(n0 + row)*KT + kb + ((ck ^ (row & 7)) << 3)],
                        &lb[buf][(t*256 + wv*64) * 8]);
        }
    };

    f32x4 acc[4][2];
    #pragma unroll
    for (int i = 0; i < 4; i++)
        #pragma unroll
        for (int j = 0; j < 2; j++) acc[i][j] = zero4();

    stage(0, 0);
    __syncthreads();

    for (int kt = 0; kt < NK; kt++) {
        int cur = kt & 1;
        if (kt + 1 < NK) stage(kt + 1, cur ^ 1);
        const bf16* lab = la[cur];
        const bf16* lbb = lb[cur];
        #pragma unroll
        for (int ks = 0; ks < 64; ks += 32) {
            int lc = (ks >> 3) + lg;
            bf16x8 af[4], bfr[2];
            #pragma unroll
            for (int i = 0; i < 4; i++) {
                int ri = wr*64 + i*16 + l15;
                af[i] = *(const bf16x8*)&lab[ri*64 + ((lc ^ (ri & 7)) << 3)];
            }
            #pragma unroll
            for (int j = 0; j < 2; j++) {
                int rj = wc*32 + j*16 + l15;
                bfr[j] = *(const bf16x8*)&lbb[rj*64 + ((lc ^ (rj & 7)) << 3)];
            }
            #pragma unroll
            for (int i = 0; i < 4; i++)
                #pragma unroll
                for (int j = 0; j < 2; j++)
                    acc[i][j] = __builtin_amdgcn_mfma_f32_16x16x32_bf16(af[i], bfr[j], acc[i][j], 0, 0, 0);
        }
        __syncthreads();   // drains next-stage loads (vmcnt 0) + barrier
    }

    if constexpr (EPI == 4) {
        // residual add + channel-first transposed store: out[b][col][lin]
        #pragma unroll
        for (int i = 0; i < 4; i++) {
            #pragma unroll
            for (int j = 0; j < 2; j++) {
                int row0 = m0 + wr*64 + i*16 + lg*4;
                int col = n0 + wc*32 + j*16 + l15;
                f32x4 o;
                #pragma unroll
                for (int r = 0; r < 4; r++)
                    o[r] = acc[i][j][r] + bias[col] + resid[(size_t)(row0 + r)*NT + col];
                int bb2 = row0 >= 25088;
                size_t off = (size_t)bb2*192*25088 + (size_t)col*25088 + (row0 - bb2*25088);
                *(f32x4*)&((float*)outp)[off] = o;
            }
        }
    } else {
        #pragma unroll
        for (int i = 0; i < 4; i++) {
            #pragma unroll
            for (int j = 0; j < 2; j++) {
                #pragma unroll
                for (int r = 0; r < 4; r++) {
                    int row = m0 + wr*64 + i*16 + lg*4 + r;
                    int col = n0 + wc*32 + j*16 + l15;
                    float v = acc[i][j][r] + bias[col];
                    size_t oidx = (size_t)row * NT + col;
                    if constexpr (EPI == 0) {
                        ((bf16*)outp)[oidx] = (bf16)v;
                    } else if constexpr (EPI == 1) {
                        ((float*)outp)[oidx] = v;
                    } else if constexpr (EPI == 2) {
                        float gl = 0.5f * v * (1.0f + erff(v * 0.70710678118654752f));
                        ((bf16*)outp)[oidx] = (bf16)gl;
                    }
                }
            }
        }
    }
}

// K3: attention, one block per (WINDOW, HEAD). grid 3072, block 128 (2 waves).
// Wave 0 -> row-tiles 0..3, wave 1 -> 4..6. K frags in registers, Q
// prefetched one row-tile ahead (static 2-reg rotation).
__global__ __launch_bounds__(128) void attn_k(
    const bf16* __restrict__ qkv, const float* __restrict__ biasT,
    const float* __restrict__ maskm, bf16* __restrict__ aout)
{
    __shared__ bf16 VT[32*128];      // [d][key ^ ((d&7)<<3)], keys>=98 zero
    __shared__ bf16 Pl[2*16*136];
    int blk = blockIdx.x;
    int t8 = (blk & 7) * 384 + (blk >> 3);   // XCD-contiguous task id
    int b_ = t8 / 6, head = t8 % 6;
    int tid = threadIdx.x, lane = tid & 63, wv = tid >> 6;
    int l15 = lane & 15, lg = (lane >> 4) & 3;
    int wib = b_ & 255;
    const bf16* base = qkv + (size_t)b_*98*576;

    // ---- phase 0: zero VT fully + P pad cols (112..127) ----
    {
        unsigned int* vz = (unsigned int*)VT;
        for (int e = tid; e < 2048; e += 128) vz[e] = 0u;
        unsigned int* pz = (unsigned int*)Pl;
        for (int e = tid; e < 256; e += 128) {
            int w2 = e >> 7, rem = e & 127;
            int row = rem >> 3, cp = rem & 7;
            pz[(w2*16 + row)*68 + 56 + cp] = 0u;
        }
    }
    __syncthreads();
    // ---- phase 1: stage V^T slice; k varies with lane (conflict-free) ----
    {
        int dq = tid >> 5;               // d-octet 0..3
        int kl = tid & 31;
        const bf16* vbase = base + 384 + head*32 + dq*8;
        #pragma unroll
        for (int kr = 0; kr < 4; kr++) {
            int k = kr*32 + kl;
            if (k < 98) {
                bf16x8 v8 = *(const bf16x8*)&vbase[(size_t)k*576];
                #pragma unroll
                for (int j = 0; j < 8; j++)
                    VT[(dq*8 + j)*128 + (k ^ (j << 3))] = v8[j];
            }
        }
    }
    __syncthreads();

    // ---- K fragments into registers (reused across row-tiles) ----
    bf16x8 kfr[7];
    #pragma unroll
    for (int j = 0; j < 7; j++) {
        int krow = j*16 + l15; if (krow > 97) krow = 97;   // NaN guard
        kfr[j] = *(const bf16x8*)&base[(size_t)krow*576 + 192 + head*32 + lg*8];
    }

    const float scale = 0.17677669529663687f;   // 32^-0.5
    bf16* Pw = Pl + wv*16*136;
    const int rt0 = wv ? 4 : 0, rt1 = wv ? 7 : 4;

    auto loadQ = [&](int rt) {
        int qrow = rt*16 + l15; if (qrow > 97) qrow = 97;
        return *(const bf16x8*)&base[(size_t)qrow*576 + head*32 + lg*8];
    };
    bf16x8 qf = loadQ(rt0);

    #pragma unroll 1
    for (int rt = rt0; rt < rt1; rt++) {
        bf16x8 qnext = qf;
        if (rt + 1 < rt1) qnext = loadQ(rt + 1);   // prefetch next row-tile's Q
        // ---- S = Q K^T ----
        f32x4 sacc[7];
        #pragma unroll
        for (int j = 0; j < 7; j++) sacc[j] = zero4();
        #pragma unroll
        for (int j = 0; j < 7; j++)
            sacc[j] = __builtin_amdgcn_mfma_f32_16x16x32_bf16(qf, kfr[j], sacc[j], 0, 0, 0);
        // ---- softmax (bias table has -1e30 in pad cols) ----
        #pragma unroll
        for (int r = 0; r < 4; r++) {
            int nq = rt*16 + lg*4 + r;
            int nqc = nq > 97 ? 97 : nq;
            const float* bb = biasT + (head*98 + nqc)*112;
            const float* mm = maskm + ((size_t)wib*98 + nqc)*98;
            float sv[7];
            float m = -1e30f;
            #pragma unroll
            for (int j = 0; j < 7; j++) {
                int nk = j*16 + l15;
                float v = sacc[j][r]*scale + bb[nk];
                if (nk < 98) v += mm[nk];
                sv[j] = v; m = fmaxf(m, v);
            }
            #pragma unroll
            for (int d = 1; d < 16; d <<= 1) m = fmaxf(m, __shfl_xor(m, d));
            float sum = 0.f;
            #pragma unroll
            for (int j = 0; j < 7; j++) { sv[j] = __expf(sv[j] - m); sum += sv[j]; }
            #pragma unroll
            for (int d = 1; d < 16; d <<= 1) sum += __shfl_xor(sum, d);
            float inv = 1.0f / sum;
            #pragma unroll
            for (int j = 0; j < 7; j++)
                Pw[(lg*4 + r)*136 + j*16 + l15] = (bf16)(sv[j]*inv);
        }
        // ---- O = P V ----
        #pragma unroll
        for (int dt = 0; dt < 2; dt++) {
            int dl = dt*16 + l15;                 // local d within head slice
            int xr = (dl & 7) << 3;
            f32x4 oacc = zero4();
            #pragma unroll
            for (int kc = 0; kc < 4; kc++) {
                bf16x8 pf = *(const bf16x8*)&Pw[l15*136 + kc*32 + lg*8];
                bf16x8 vf = *(const bf16x8*)&VT[dl*128 + ((kc*32 + lg*8) ^ xr)];
                oacc = __builtin_amdgcn_mfma_f32_16x16x32_bf16(pf, vf, oacc, 0, 0, 0);
            }
            #pragma unroll
            for (int r = 0; r < 4; r++) {
                int row = rt*16 + lg*4 + r;
                if (row < 98)
                    aout[((size_t)b_*98 + row)*192 + head*32 + dt*16 + l15] = (bf16)oacc[r];
            }
        }
        qf = qnext;
    }
}

// K5: window reverse + roll-back + residual(x) + LN2. grid 896.
__global__ __launch_bounds__(256) void rev_res_ln2_k(
    const float* __restrict__ x, const float* __restrict__ pw,
    const float* __restrict__ g2, const float* __restrict__ b2,
    float* __restrict__ x1, bf16* __restrict__ xn2)
{
    __shared__ float tile[56*193];
    __shared__ float mu[56], rs[56];
    int blk = blockIdx.x;
    int bb = blk / 448; int r = blk % 448; int t = r / 56; int h = r % 56;
    int ts = (t + 7) & 7;
    int hs = h - 3; if (hs < 0) hs += 56;
    int tid = threadIdx.x;
    const float* xs = x + ((size_t)bb*1536 + t)*3136 + h*56;
    for (int e = tid; e < 192*56; e += 256) {
        int c = e / 56, w = e % 56;
        tile[w*193 + c] = xs[(size_t)c*25088 + w];
    }
    __syncthreads();
    int tb = ts >> 1, wt = ts & 1, hb = hs / 7, wh = hs % 7;
    for (int e = tid; e < 56*192; e += 256) {
        int w = e / 192, c = e % 192;
        int wsp = w - 3; if (wsp < 0) wsp += 56;
        int wb = wsp / 7, ww = wsp % 7;
        size_t tok = (size_t)(bb*256 + tb*64 + hb*8 + wb)*98 + wt*49 + wh*7 + ww;
        tile[w*193 + c] += pw[tok*192 + c];
    }
    __syncthreads();
    if (tid < 224) {
        int row = tid >> 2, q = tid & 3;
        float s = 0.f, s2 = 0.f;
        for (int c = q*48; c < q*48 + 48; c++) {
            float v = tile[row*193 + c]; s += v; s2 += v*v;
        }
        s  += __shfl_xor(s, 1);  s  += __shfl_xor(s, 2);
        s2 += __shfl_xor(s2, 1); s2 += __shfl_xor(s2, 2);
        if (q == 0) {
            float m = s * (1.0f/192.0f);
            mu[row] = m;
            rs[row] = rsqrtf(s2 * (1.0f/192.0f) - m*m + 1e-5f);
        }
    }
    __syncthreads();
    size_t tok0 = ((size_t)(bb*8 + t)*56 + h)*56;
    for (int e = tid; e < 56*192; e += 256) {
        int w = e / 192, c = e % 192;
        float v = tile[w*193 + c];
        x1[(tok0 + w)*192 + c] = v;
        xn2[(tok0 + w)*192 + c] = (bf16)((v - mu[w]) * rs[w] * g2[c] + b2[c]);
    }
}

// ---------------------------------------------------------------------------
extern "C" void kernel_launch(void* const* d_in, const int* in_sizes, int n_in,
                              void* d_out, int out_size, void* d_ws, size_t ws_size,
                              hipStream_t stream)
{
    const float* x     = (const float*)d_in[0];
    const float* maskm = (const float*)d_in[1];
    const float* n1g   = (const float*)d_in[2];
    const float* n1b   = (const float*)d_in[3];
    const float* qkvw  = (const float*)d_in[4];
    const float* qkvb  = (const float*)d_in[5];
    const float* projw = (const float*)d_in[6];
    const float* projb = (const float*)d_in[7];
    const float* rpb   = (const float*)d_in[8];
    const float* n2g   = (const float*)d_in[9];
    const float* n2b   = (const float*)d_in[10];
    const float* f1w   = (const float*)d_in[11];
    const float* f1b   = (const float*)d_in[12];
    const float* f2w   = (const float*)d_in[13];
    const float* f2b   = (const float*)d_in[14];

    char* ws = (char*)d_ws;
    // weights (transposed bf16) + bias table
    bf16*  qkv_wt  = (bf16*)(ws + 0);          // 221184
    bf16*  proj_wt = (bf16*)(ws + 221184);     // 73728
    bf16*  fc1_wt  = (bf16*)(ws + 294912);     // 294912
    bf16*  fc2_wt  = (bf16*)(ws + 589824);     // 294912
    float* biasT   = (float*)(ws + 884736);    // 263424
    // region A: xw (bf16, 19.27MB) -> reused as attn_out
    bf16* xw   = (bf16*)(ws + 1179648);
    bf16* aout = xw;
    // region B: qkv (bf16, 57.8MB) -> reused as proj-out f32
    char* Bp = ws + 1179648 + 19267584;
    bf16*  qkv  = (bf16*)Bp;
    float* pwin = (float*)Bp;
    // region C: x1 f32; region D: xn2 bf16; region E: h1 bf16
    char* Cp = Bp + 57802752;
    float* x1  = (float*)Cp;
    bf16*  xn2 = (bf16*)(Cp + 38535168);
    bf16*  h1  = (bf16*)(Cp + 38535168 + 19267584);

    prep_w_k<<<576, 256, 0, stream>>>(qkvw, projw, f1w, f2w, qkv_wt, proj_wt, fc1_wt, fc2_wt);
    prep_bias_k<<<258, 256, 0, stream>>>(rpb, biasT);
    ln1_window_k<<<896, 256, 0, stream>>>(x, n1g, n1b, xw);
    gemm_k<192, 576, 0><<<392*9, 256, 0, stream>>>(xw, qkv_wt, qkvb, nullptr, qkv);
    attn_k<<<3072, 128, 0, stream>>>(qkv, biasT, maskm, aout);
    gemm_k<192, 192, 1><<<392*3, 256, 0, stream>>>(aout, proj_wt, projb, nullptr, pwin);
    rev_res_ln2_k<<<896, 256, 0, stream>>>(x, pwin, n2g, n2b, x1, xn2);
    gemm_k<192, 768, 2><<<392*12, 256, 0, stream>>>(xn2, fc1_wt, f1b, nullptr, h1);
    gemm_k<768, 192, 4><<<392*3, 256, 0, stream>>>(h1, fc2_wt, f2b, x1, (float*)d_out);
}

// Round 7
// 241.948 us; speedup vs baseline: 1.2543x; 1.1466x over previous
//
#include <hip/hip_runtime.h>
#include <hip/hip_bf16.h>
#include <math.h>

#define DEV __device__ __forceinline__

typedef __bf16 bf16;
typedef __bf16 bf16x8 __attribute__((ext_vector_type(8)));
typedef float f32x4 __attribute__((ext_vector_type(4)));

DEV f32x4 zero4() { f32x4 z; z[0]=0.f; z[1]=0.f; z[2]=0.f; z[3]=0.f; return z; }

DEV void gload_lds16(const bf16* g, bf16* l) {
    __builtin_amdgcn_global_load_lds(
        (const __attribute__((address_space(1))) void*)g,
        (__attribute__((address_space(3))) void*)l, 16, 0, 0);
}

// ---------------------------------------------------------------------------
// Geometry: B=2, C=192, T=8, H=56, W=56; window (2,7,7) N=98; shift (1,3,3)
// windows: 4*8*8=256 per batch, B_=512; tokens M = 50176
// ---------------------------------------------------------------------------

// K0: transpose weights to (N,K) k-contiguous bf16
__global__ __launch_bounds__(256) void prep_w_k(
    const float* __restrict__ qw, const float* __restrict__ pw,
    const float* __restrict__ f1, const float* __restrict__ f2,
    bf16* __restrict__ qwt, bf16* __restrict__ pwt,
    bf16* __restrict__ f1t, bf16* __restrict__ f2t)
{
    int i = blockIdx.x * 256 + threadIdx.x;
    if (i < 576*192) { int n = i / 192, k = i % 192; qwt[i] = (bf16)qw[(size_t)k*576 + n]; }
    if (i < 192*192) { int n = i / 192, k = i % 192; pwt[i] = (bf16)pw[(size_t)k*192 + n]; }
    if (i < 768*192) { int n = i / 192, k = i % 192; f1t[i] = (bf16)f1[(size_t)k*768 + n]; }
    if (i < 192*768) { int n = i / 768, k = i % 768; f2t[i] = (bf16)f2[(size_t)k*192 + n]; }
}

// K0b: bias table biasT[head][nq][nk_pad=112], nk>=98 -> -1e30.
__global__ __launch_bounds__(256) void prep_bias_k(
    const float* __restrict__ rpb, float* __restrict__ biasT)
{
    int i = blockIdx.x * 256 + threadIdx.x;
    if (i >= 6*98*112) return;
    int nk = i % 112; int t = i / 112; int nq = t % 98; int h = t / 98;
    float v;
    if (nk < 98) {
        int t1 = nq/49, r1 = nq%49, h1 = r1/7, w1 = r1%7;
        int t2 = nk/49, r2 = nk%49, h2 = r2/7, w2 = r2%7;
        int idx = (t1 - t2 + 1)*169 + (h1 - h2 + 6)*13 + (w1 - w2 + 6);
        v = rpb[idx*6 + h];
    } else {
        v = -1e30f;
    }
    biasT[i] = v;
}

// K1: LN1 + cyclic shift + window partition. grid = B*T*H = 896.
__global__ __launch_bounds__(256) void ln1_window_k(
    const float* __restrict__ x, const float* __restrict__ g,
    const float* __restrict__ bta, bf16* __restrict__ xw)
{
    __shared__ float tile[56*193];
    __shared__ float mu[56], rs[56];
    int blk = blockIdx.x;
    int bb = blk / 448; int r = blk % 448; int ts = r / 56; int hs = r % 56;
    int t = (ts + 1) & 7;
    int h = hs + 3; if (h >= 56) h -= 56;
    int tid = threadIdx.x;
    const float* xs = x + ((size_t)bb*1536 + t)*3136 + h*56;
    for (int e = tid; e < 192*56; e += 256) {
        int c = e / 56, w = e % 56;
        int wsp = w - 3; if (wsp < 0) wsp += 56;
        tile[wsp*193 + c] = xs[(size_t)c*25088 + w];
    }
    __syncthreads();
    if (tid < 224) {                       // 4 lanes per row, wave-parallel stats
        int row = tid >> 2, q = tid & 3;
        float s = 0.f, s2 = 0.f;
        for (int c = q*48; c < q*48 + 48; c++) {
            float v = tile[row*193 + c]; s += v; s2 += v*v;
        }
        s  += __shfl_xor(s, 1);  s  += __shfl_xor(s, 2);
        s2 += __shfl_xor(s2, 1); s2 += __shfl_xor(s2, 2);
        if (q == 0) {
            float m = s * (1.0f/192.0f);
            mu[row] = m;
            rs[row] = rsqrtf(s2 * (1.0f/192.0f) - m*m + 1e-5f);
        }
    }
    __syncthreads();
    int tb = ts >> 1, wt = ts & 1;
    int hb = hs / 7, wh = hs % 7;
    for (int e = tid; e < 56*192; e += 256) {
        int wpos = e / 192, c = e % 192;
        float v = (tile[wpos*193 + c] - mu[wpos]) * rs[wpos] * g[c] + bta[c];
        int wb = wpos / 7, ww = wpos % 7;
        int widx = bb*256 + tb*64 + hb*8 + wb;
        int n = wt*49 + wh*7 + ww;
        xw[((size_t)widx*98 + n)*192 + c] = (bf16)v;
    }
}

// Generic bf16 MFMA GEMM: C(M,NT) = A(M,KT) @ BT(NT,KT)^T + bias, M=50176.
// BM=128 BN=64 BK=64, double-buffered LDS (2-phase pipeline).
// XCD-affinity swizzle: all NTILES n-tiles of one 128-row A-strip land on
// the SAME XCD (blk&7) so the strip is fetched into that L2 exactly once.
// NM=392 strips, 392%8==0 -> bijective mapping.
// EPI: 0 bf16; 1 f32; 2 gelu bf16; 4 resid + channel-first transpose -> d_out.
template<int KT, int NT, int EPI>
__global__ __launch_bounds__(256) void gemm_k(
    const bf16* __restrict__ A, const bf16* __restrict__ BT,
    const float* __restrict__ bias, const float* __restrict__ resid,
    void* __restrict__ outp)
{
    __shared__ bf16 la[2][128*64];
    __shared__ bf16 lb[2][64*64];
    constexpr int NTILES = NT / 64;
    constexpr int NK = KT / 64;
    constexpr int SPX = 392 / 8;           // A-strips per XCD
    int blk = blockIdx.x;
    int xcd = blk & 7, ix = blk >> 3;
    int m0 = (xcd * SPX + ix / NTILES) * 128;
    int n0 = (ix % NTILES) * 64;
    int tid = threadIdx.x;
    int lane = tid & 63;
    int wv = tid >> 6;
    int wr = wv >> 1, wc = wv & 1;
    int l15 = lane & 15, lg = lane >> 4;

    auto stage = [&](int kt, int buf) {
        int kb = kt * 64;
        #pragma unroll
        for (int t = 0; t < 4; t++) {
            int e = t*256 + wv*64 + lane;
            int row = e >> 3, ck = e & 7;
            gload_lds16(&A[(size_t)(m0 + row)*KT + kb + ((ck ^ (row & 7)) << 3)],
                        &la[buf][(t*256 + wv*64) * 8]);
        }
        #pragma unroll
        for (int t = 0; t < 2; t++) {
            int e = t*256 + wv*64 + lane;
            int row = e >> 3, ck = e & 7;
            gload_lds16(&BT[(size_t)(n0 + row)*KT + kb + ((ck ^ (row & 7)) << 3)],
                        &lb[buf][(t*256 + wv*64) * 8]);
        }
    };

    f32x4 acc[4][2];
    #pragma unroll
    for (int i = 0; i < 4; i++)
        #pragma unroll
        for (int j = 0; j < 2; j++) acc[i][j] = zero4();

    stage(0, 0);
    __syncthreads();

    for (int kt = 0; kt < NK; kt++) {
        int cur = kt & 1;
        if (kt + 1 < NK) stage(kt + 1, cur ^ 1);
        const bf16* lab = la[cur];
        const bf16* lbb = lb[cur];
        #pragma unroll
        for (int ks = 0; ks < 64; ks += 32) {
            int lc = (ks >> 3) + lg;
            bf16x8 af[4], bfr[2];
            #pragma unroll
            for (int i = 0; i < 4; i++) {
                int ri = wr*64 + i*16 + l15;
                af[i] = *(const bf16x8*)&lab[ri*64 + ((lc ^ (ri & 7)) << 3)];
            }
            #pragma unroll
            for (int j = 0; j < 2; j++) {
                int rj = wc*32 + j*16 + l15;
                bfr[j] = *(const bf16x8*)&lbb[rj*64 + ((lc ^ (rj & 7)) << 3)];
            }
            #pragma unroll
            for (int i = 0; i < 4; i++)
                #pragma unroll
                for (int j = 0; j < 2; j++)
                    acc[i][j] = __builtin_amdgcn_mfma_f32_16x16x32_bf16(af[i], bfr[j], acc[i][j], 0, 0, 0);
        }
        __syncthreads();   // drains next-stage loads (vmcnt 0) + barrier
    }

    if constexpr (EPI == 4) {
        // residual add + channel-first transposed store: out[b][col][lin]
        #pragma unroll
        for (int i = 0; i < 4; i++) {
            #pragma unroll
            for (int j = 0; j < 2; j++) {
                int row0 = m0 + wr*64 + i*16 + lg*4;
                int col = n0 + wc*32 + j*16 + l15;
                f32x4 o;
                #pragma unroll
                for (int r = 0; r < 4; r++)
                    o[r] = acc[i][j][r] + bias[col] + resid[(size_t)(row0 + r)*NT + col];
                int bb2 = row0 >= 25088;
                size_t off = (size_t)bb2*192*25088 + (size_t)col*25088 + (row0 - bb2*25088);
                *(f32x4*)&((float*)outp)[off] = o;
            }
        }
    } else {
        #pragma unroll
        for (int i = 0; i < 4; i++) {
            #pragma unroll
            for (int j = 0; j < 2; j++) {
                #pragma unroll
                for (int r = 0; r < 4; r++) {
                    int row = m0 + wr*64 + i*16 + lg*4 + r;
                    int col = n0 + wc*32 + j*16 + l15;
                    float v = acc[i][j][r] + bias[col];
                    size_t oidx = (size_t)row * NT + col;
                    if constexpr (EPI == 0) {
                        ((bf16*)outp)[oidx] = (bf16)v;
                    } else if constexpr (EPI == 1) {
                        ((float*)outp)[oidx] = v;
                    } else if constexpr (EPI == 2) {
                        float gl = 0.5f * v * (1.0f + erff(v * 0.70710678118654752f));
                        ((bf16*)outp)[oidx] = (bf16)gl;
                    }
                }
            }
        }
    }
}

// K3: attention, one block per (WINDOW, HEAD). grid 3072, block 128 (2 waves).
// Wave 0 -> row-tiles 0..3, wave 1 -> 4..6. K frags in registers, Q
// prefetched one row-tile ahead (static 2-reg rotation).
__global__ __launch_bounds__(128) void attn_k(
    const bf16* __restrict__ qkv, const float* __restrict__ biasT,
    const float* __restrict__ maskm, bf16* __restrict__ aout)
{
    __shared__ bf16 VT[32*128];      // [d][key ^ ((d&7)<<3)], keys>=98 zero
    __shared__ bf16 Pl[2*16*136];
    int blk = blockIdx.x;
    int t8 = (blk & 7) * 384 + (blk >> 3);   // XCD-contiguous task id
    int b_ = t8 / 6, head = t8 % 6;
    int tid = threadIdx.x, lane = tid & 63, wv = tid >> 6;
    int l15 = lane & 15, lg = (lane >> 4) & 3;
    int wib = b_ & 255;
    const bf16* base = qkv + (size_t)b_*98*576;

    // ---- phase 0: zero VT fully + P pad cols (112..127) ----
    {
        unsigned int* vz = (unsigned int*)VT;
        for (int e = tid; e < 2048; e += 128) vz[e] = 0u;
        unsigned int* pz = (unsigned int*)Pl;
        for (int e = tid; e < 256; e += 128) {
            int w2 = e >> 7, rem = e & 127;
            int row = rem >> 3, cp = rem & 7;
            pz[(w2*16 + row)*68 + 56 + cp] = 0u;
        }
    }
    __syncthreads();
    // ---- phase 1: stage V^T slice; k varies with lane (conflict-free) ----
    {
        int dq = tid >> 5;               // d-octet 0..3
        int kl = tid & 31;
        const bf16* vbase = base + 384 + head*32 + dq*8;
        #pragma unroll
        for (int kr = 0; kr < 4; kr++) {
            int k = kr*32 + kl;
            if (k < 98) {
                bf16x8 v8 = *(const bf16x8*)&vbase[(size_t)k*576];
                #pragma unroll
                for (int j = 0; j < 8; j++)
                    VT[(dq*8 + j)*128 + (k ^ (j << 3))] = v8[j];
            }
        }
    }
    __syncthreads();

    // ---- K fragments into registers (reused across row-tiles) ----
    bf16x8 kfr[7];
    #pragma unroll
    for (int j = 0; j < 7; j++) {
        int krow = j*16 + l15; if (krow > 97) krow = 97;   // NaN guard
        kfr[j] = *(const bf16x8*)&base[(size_t)krow*576 + 192 + head*32 + lg*8];
    }

    const float scale = 0.17677669529663687f;   // 32^-0.5
    bf16* Pw = Pl + wv*16*136;
    const int rt0 = wv ? 4 : 0, rt1 = wv ? 7 : 4;

    auto loadQ = [&](int rt) {
        int qrow = rt*16 + l15; if (qrow > 97) qrow = 97;
        return *(const bf16x8*)&base[(size_t)qrow*576 + head*32 + lg*8];
    };
    bf16x8 qf = loadQ(rt0);

    #pragma unroll 1
    for (int rt = rt0; rt < rt1; rt++) {
        bf16x8 qnext = qf;
        if (rt + 1 < rt1) qnext = loadQ(rt + 1);   // prefetch next row-tile's Q
        // ---- S = Q K^T ----
        f32x4 sacc[7];
        #pragma unroll
        for (int j = 0; j < 7; j++) sacc[j] = zero4();
        #pragma unroll
        for (int j = 0; j < 7; j++)
            sacc[j] = __builtin_amdgcn_mfma_f32_16x16x32_bf16(qf, kfr[j], sacc[j], 0, 0, 0);
        // ---- softmax (bias table has -1e30 in pad cols) ----
        #pragma unroll
        for (int r = 0; r < 4; r++) {
            int nq = rt*16 + lg*4 + r;
            int nqc = nq > 97 ? 97 : nq;
            const float* bb = biasT + (head*98 + nqc)*112;
            const float* mm = maskm + ((size_t)wib*98 + nqc)*98;
            float sv[7];
            float m = -1e30f;
            #pragma unroll
            for (int j = 0; j < 7; j++) {
                int nk = j*16 + l15;
                float v = sacc[j][r]*scale + bb[nk];
                if (nk < 98) v += mm[nk];
                sv[j] = v; m = fmaxf(m, v);
            }
            #pragma unroll
            for (int d = 1; d < 16; d <<= 1) m = fmaxf(m, __shfl_xor(m, d));
            float sum = 0.f;
            #pragma unroll
            for (int j = 0; j < 7; j++) { sv[j] = __expf(sv[j] - m); sum += sv[j]; }
            #pragma unroll
            for (int d = 1; d < 16; d <<= 1) sum += __shfl_xor(sum, d);
            float inv = 1.0f / sum;
            #pragma unroll
            for (int j = 0; j < 7; j++)
                Pw[(lg*4 + r)*136 + j*16 + l15] = (bf16)(sv[j]*inv);
        }
        // ---- O = P V ----
        #pragma unroll
        for (int dt = 0; dt < 2; dt++) {
            int dl = dt*16 + l15;                 // local d within head slice
            int xr = (dl & 7) << 3;
            f32x4 oacc = zero4();
            #pragma unroll
            for (int kc = 0; kc < 4; kc++) {
                bf16x8 pf = *(const bf16x8*)&Pw[l15*136 + kc*32 + lg*8];
                bf16x8 vf = *(const bf16x8*)&VT[dl*128 + ((kc*32 + lg*8) ^ xr)];
                oacc = __builtin_amdgcn_mfma_f32_16x16x32_bf16(pf, vf, oacc, 0, 0, 0);
            }
            #pragma unroll
            for (int r = 0; r < 4; r++) {
                int row = rt*16 + lg*4 + r;
                if (row < 98)
                    aout[((size_t)b_*98 + row)*192 + head*32 + dt*16 + l15] = (bf16)oacc[r];
            }
        }
        qf = qnext;
    }
}

// K5: window reverse + roll-back + residual(x) + LN2. grid 896.
__global__ __launch_bounds__(256) void rev_res_ln2_k(
    const float* __restrict__ x, const float* __restrict__ pw,
    const float* __restrict__ g2, const float* __restrict__ b2,
    float* __restrict__ x1, bf16* __restrict__ xn2)
{
    __shared__ float tile[56*193];
    __shared__ float mu[56], rs[56];
    int blk = blockIdx.x;
    int bb = blk / 448; int r = blk % 448; int t = r / 56; int h = r % 56;
    int ts = (t + 7) & 7;
    int hs = h - 3; if (hs < 0) hs += 56;
    int tid = threadIdx.x;
    const float* xs = x + ((size_t)bb*1536 + t)*3136 + h*56;
    for (int e = tid; e < 192*56; e += 256) {
        int c = e / 56, w = e % 56;
        tile[w*193 + c] = xs[(size_t)c*25088 + w];
    }
    __syncthreads();
    int tb = ts >> 1, wt = ts & 1, hb = hs / 7, wh = hs % 7;
    for (int e = tid; e < 56*192; e += 256) {
        int w = e / 192, c = e % 192;
        int wsp = w - 3; if (wsp < 0) wsp += 56;
        int wb = wsp / 7, ww = wsp % 7;
        size_t tok = (size_t)(bb*256 + tb*64 + hb*8 + wb)*98 + wt*49 + wh*7 + ww;
        tile[w*193 + c] += pw[tok*192 + c];
    }
    __syncthreads();
    if (tid < 224) {
        int row = tid >> 2, q = tid & 3;
        float s = 0.f, s2 = 0.f;
        for (int c = q*48; c < q*48 + 48; c++) {
            float v = tile[row*193 + c]; s += v; s2 += v*v;
        }
        s  += __shfl_xor(s, 1);  s  += __shfl_xor(s, 2);
        s2 += __shfl_xor(s2, 1); s2 += __shfl_xor(s2, 2);
        if (q == 0) {
            float m = s * (1.0f/192.0f);
            mu[row] = m;
            rs[row] = rsqrtf(s2 * (1.0f/192.0f) - m*m + 1e-5f);
        }
    }
    __syncthreads();
    size_t tok0 = ((size_t)(bb*8 + t)*56 + h)*56;
    for (int e = tid; e < 56*192; e += 256) {
        int w = e / 192, c = e % 192;
        float v = tile[w*193 + c];
        x1[(tok0 + w)*192 + c] = v;
        xn2[(tok0 + w)*192 + c] = (bf16)((v - mu[w]) * rs[w] * g2[c] + b2[c]);
    }
}

// ---------------------------------------------------------------------------
extern "C" void kernel_launch(void* const* d_in, const int* in_sizes, int n_in,
                              void* d_out, int out_size, void* d_ws, size_t ws_size,
                              hipStream_t stream)
{
    const float* x     = (const float*)d_in[0];
    const float* maskm = (const float*)d_in[1];
    const float* n1g   = (const float*)d_in[2];
    const float* n1b   = (const float*)d_in[3];
    const float* qkvw  = (const float*)d_in[4];
    const float* qkvb  = (const float*)d_in[5];
    const float* projw = (const float*)d_in[6];
    const float* projb = (const float*)d_in[7];
    const float* rpb   = (const float*)d_in[8];
    const float* n2g   = (const float*)d_in[9];
    const float* n2b   = (const float*)d_in[10];
    const float* f1w   = (const float*)d_in[11];
    const float* f1b   = (const float*)d_in[12];
    const float* f2w   = (const float*)d_in[13];
    const float* f2b   = (const float*)d_in[14];

    char* ws = (char*)d_ws;
    // weights (transposed bf16) + bias table
    bf16*  qkv_wt  = (bf16*)(ws + 0);          // 221184
    bf16*  proj_wt = (bf16*)(ws + 221184);     // 73728
    bf16*  fc1_wt  = (bf16*)(ws + 294912);     // 294912
    bf16*  fc2_wt  = (bf16*)(ws + 589824);     // 294912
    float* biasT   = (float*)(ws + 884736);    // 263424
    // region A: xw (bf16, 19.27MB) -> reused as attn_out
    bf16* xw   = (bf16*)(ws + 1179648);
    bf16* aout = xw;
    // region B: qkv (bf16, 57.8MB) -> reused as proj-out f32
    char* Bp = ws + 1179648 + 19267584;
    bf16*  qkv  = (bf16*)Bp;
    float* pwin = (float*)Bp;
    // region C: x1 f32; region D: xn2 bf16; region E: h1 bf16
    char* Cp = Bp + 57802752;
    float* x1  = (float*)Cp;
    bf16*  xn2 = (bf16*)(Cp + 38535168);
    bf16*  h1  = (bf16*)(Cp + 38535168 + 19267584);

    prep_w_k<<<576, 256, 0, stream>>>(qkvw, projw, f1w, f2w, qkv_wt, proj_wt, fc1_wt, fc2_wt);
    prep_bias_k<<<258, 256, 0, stream>>>(rpb, biasT);
    ln1_window_k<<<896, 256, 0, stream>>>(x, n1g, n1b, xw);
    gemm_k<192, 576, 0><<<392*9, 256, 0, stream>>>(xw, qkv_wt, qkvb, nullptr, qkv);
    attn_k<<<3072, 128, 0, stream>>>(qkv, biasT, maskm, aout);
    gemm_k<192, 192, 1><<<392*3, 256, 0, stream>>>(aout, proj_wt, projb, nullptr, pwin);
    rev_res_ln2_k<<<896, 256, 0, stream>>>(x, pwin, n2g, n2b, x1, xn2);
    gemm_k<192, 768, 2><<<392*12, 256, 0, stream>>>(xn2, fc1_wt, f1b, nullptr, h1);
    gemm_k<768, 192, 4><<<392*3, 256, 0, stream>>>(h1, fc2_wt, f2b, x1, (float*)d_out);
}

// Round 8
// 236.155 us; speedup vs baseline: 1.2851x; 1.0245x over previous
//
#include <hip/hip_runtime.h>
#include <hip/hip_bf16.h>
#include <math.h>

#define DEV __device__ __forceinline__

typedef __bf16 bf16;
typedef __bf16 bf16x8 __attribute__((ext_vector_type(8)));
typedef float f32x4 __attribute__((ext_vector_type(4)));

DEV f32x4 zero4() { f32x4 z; z[0]=0.f; z[1]=0.f; z[2]=0.f; z[3]=0.f; return z; }

DEV void gload_lds16(const bf16* g, bf16* l) {
    __builtin_amdgcn_global_load_lds(
        (const __attribute__((address_space(1))) void*)g,
        (__attribute__((address_space(3))) void*)l, 16, 0, 0);
}

// ---------------------------------------------------------------------------
// Geometry: B=2, C=192, T=8, H=56, W=56; window (2,7,7) N=98; shift (1,3,3)
// windows: 4*8*8=256 per batch, B_=512; tokens M = 50176
// ---------------------------------------------------------------------------

// K0: transpose weights to (N,K) k-contiguous bf16
__global__ __launch_bounds__(256) void prep_w_k(
    const float* __restrict__ qw, const float* __restrict__ pw,
    const float* __restrict__ f1, const float* __restrict__ f2,
    bf16* __restrict__ qwt, bf16* __restrict__ pwt,
    bf16* __restrict__ f1t, bf16* __restrict__ f2t)
{
    int i = blockIdx.x * 256 + threadIdx.x;
    if (i < 576*192) { int n = i / 192, k = i % 192; qwt[i] = (bf16)qw[(size_t)k*576 + n]; }
    if (i < 192*192) { int n = i / 192, k = i % 192; pwt[i] = (bf16)pw[(size_t)k*192 + n]; }
    if (i < 768*192) { int n = i / 192, k = i % 192; f1t[i] = (bf16)f1[(size_t)k*768 + n]; }
    if (i < 192*768) { int n = i / 768, k = i % 768; f2t[i] = (bf16)f2[(size_t)k*192 + n]; }
}

// K0b: fragment-ordered bias table: biasF[((head*7+rt)*7+j)*64+lane] = f32x4
// over r; nk>=98 baked to -1e30, nq>97 clamped to row 97.
__global__ __launch_bounds__(256) void prep_biasF_k(
    const float* __restrict__ rpb, float* __restrict__ biasF)
{
    int i = blockIdx.x * 256 + threadIdx.x;   // (head,rt,j,lane)
    if (i >= 6*7*7*64) return;
    int lane = i & 63; int g = i >> 6;
    int j = g % 7; g /= 7; int rt = g % 7; int head = g / 7;
    int l15 = lane & 15, lg = lane >> 4;
    int nk = j*16 + l15;
    f32x4 o;
    #pragma unroll
    for (int r = 0; r < 4; r++) {
        int nq = rt*16 + lg*4 + r; if (nq > 97) nq = 97;
        if (nk < 98) {
            int t1 = nq/49, r1 = nq%49, h1 = r1/7, w1 = r1%7;
            int t2 = nk/49, r2 = nk%49, h2 = r2/7, w2 = r2%7;
            int idx = (t1 - t2 + 1)*169 + (h1 - h2 + 6)*13 + (w1 - w2 + 6);
            o[r] = rpb[idx*6 + head];
        } else {
            o[r] = -1e30f;
        }
    }
    *(f32x4*)&biasF[(size_t)i*4] = o;
}

// K0c: fragment-ordered mask table: maskF[((wib*7+rt)*7+j)*64+lane] = f32x4
// over r; nk>=98 -> 0 (bias already -1e30), nq clamped.
__global__ __launch_bounds__(256) void prep_maskF_k(
    const float* __restrict__ maskm, float* __restrict__ maskF)
{
    int i = blockIdx.x * 256 + threadIdx.x;   // (wib,rt,j,lane)
    if (i >= 256*7*7*64) return;
    int lane = i & 63; int g = i >> 6;
    int j = g % 7; g /= 7; int rt = g % 7; int wib = g / 7;
    int l15 = lane & 15, lg = lane >> 4;
    int nk = j*16 + l15;
    f32x4 o;
    #pragma unroll
    for (int r = 0; r < 4; r++) {
        int nq = rt*16 + lg*4 + r; if (nq > 97) nq = 97;
        o[r] = (nk < 98) ? maskm[((size_t)wib*98 + nq)*98 + nk] : 0.f;
    }
    *(f32x4*)&maskF[(size_t)i*4] = o;
}

// K1: LN1 + cyclic shift + window partition. grid = B*T*H = 896.
__global__ __launch_bounds__(256) void ln1_window_k(
    const float* __restrict__ x, const float* __restrict__ g,
    const float* __restrict__ bta, bf16* __restrict__ xw)
{
    __shared__ float tile[56*193];
    __shared__ float mu[56], rs[56];
    int blk = blockIdx.x;
    int bb = blk / 448; int r = blk % 448; int ts = r / 56; int hs = r % 56;
    int t = (ts + 1) & 7;
    int h = hs + 3; if (h >= 56) h -= 56;
    int tid = threadIdx.x;
    const float* xs = x + ((size_t)bb*1536 + t)*3136 + h*56;
    for (int e = tid; e < 192*56; e += 256) {
        int c = e / 56, w = e % 56;
        int wsp = w - 3; if (wsp < 0) wsp += 56;
        tile[wsp*193 + c] = xs[(size_t)c*25088 + w];
    }
    __syncthreads();
    if (tid < 224) {
        int row = tid >> 2, q = tid & 3;
        float s = 0.f, s2 = 0.f;
        for (int c = q*48; c < q*48 + 48; c++) {
            float v = tile[row*193 + c]; s += v; s2 += v*v;
        }
        s  += __shfl_xor(s, 1);  s  += __shfl_xor(s, 2);
        s2 += __shfl_xor(s2, 1); s2 += __shfl_xor(s2, 2);
        if (q == 0) {
            float m = s * (1.0f/192.0f);
            mu[row] = m;
            rs[row] = rsqrtf(s2 * (1.0f/192.0f) - m*m + 1e-5f);
        }
    }
    __syncthreads();
    int tb = ts >> 1, wt = ts & 1;
    int hb = hs / 7, wh = hs % 7;
    for (int e = tid; e < 56*192; e += 256) {
        int wpos = e / 192, c = e % 192;
        float v = (tile[wpos*193 + c] - mu[wpos]) * rs[wpos] * g[c] + bta[c];
        int wb = wpos / 7, ww = wpos % 7;
        int widx = bb*256 + tb*64 + hb*8 + wb;
        int n = wt*49 + wh*7 + ww;
        xw[((size_t)widx*98 + n)*192 + c] = (bf16)v;
    }
}

// Generic bf16 MFMA GEMM: C(M,NT) = A(M,KT) @ BT(NT,KT)^T + bias, M=50176.
// BM=128 BN=64 BK=64, double-buffered LDS, XCD-affinity strip swizzle.
// EPI: 0 bf16; 1 f32; 2 gelu bf16; 4 resid + channel-first transpose -> d_out.
template<int KT, int NT, int EPI>
__global__ __launch_bounds__(256) void gemm_k(
    const bf16* __restrict__ A, const bf16* __restrict__ BT,
    const float* __restrict__ bias, const float* __restrict__ resid,
    void* __restrict__ outp)
{
    __shared__ bf16 la[2][128*64];
    __shared__ bf16 lb[2][64*64];
    constexpr int NTILES = NT / 64;
    constexpr int NK = KT / 64;
    constexpr int SPX = 392 / 8;           // A-strips per XCD
    int blk = blockIdx.x;
    int xcd = blk & 7, ix = blk >> 3;
    int m0 = (xcd * SPX + ix / NTILES) * 128;
    int n0 = (ix % NTILES) * 64;
    int tid = threadIdx.x;
    int lane = tid & 63;
    int wv = tid >> 6;
    int wr = wv >> 1, wc = wv & 1;
    int l15 = lane & 15, lg = lane >> 4;

    auto stage = [&](int kt, int buf) {
        int kb = kt * 64;
        #pragma unroll
        for (int t = 0; t < 4; t++) {
            int e = t*256 + wv*64 + lane;
            int row = e >> 3, ck = e & 7;
            gload_lds16(&A[(size_t)(m0 + row)*KT + kb + ((ck ^ (row & 7)) << 3)],
                        &la[buf][(t*256 + wv*64) * 8]);
        }
        #pragma unroll
        for (int t = 0; t < 2; t++) {
            int e = t*256 + wv*64 + lane;
            int row = e >> 3, ck = e & 7;
            gload_lds16(&BT[(size_t)(n0 + row)*KT + kb + ((ck ^ (row & 7)) << 3)],
                        &lb[buf][(t*256 + wv*64) * 8]);
        }
    };

    f32x4 acc[4][2];
    #pragma unroll
    for (int i = 0; i < 4; i++)
        #pragma unroll
        for (int j = 0; j < 2; j++) acc[i][j] = zero4();

    stage(0, 0);
    __syncthreads();

    for (int kt = 0; kt < NK; kt++) {
        int cur = kt & 1;
        if (kt + 1 < NK) stage(kt + 1, cur ^ 1);
        const bf16* lab = la[cur];
        const bf16* lbb = lb[cur];
        #pragma unroll
        for (int ks = 0; ks < 64; ks += 32) {
            int lc = (ks >> 3) + lg;
            bf16x8 af[4], bfr[2];
            #pragma unroll
            for (int i = 0; i < 4; i++) {
                int ri = wr*64 + i*16 + l15;
                af[i] = *(const bf16x8*)&lab[ri*64 + ((lc ^ (ri & 7)) << 3)];
            }
            #pragma unroll
            for (int j = 0; j < 2; j++) {
                int rj = wc*32 + j*16 + l15;
                bfr[j] = *(const bf16x8*)&lbb[rj*64 + ((lc ^ (rj & 7)) << 3)];
            }
            #pragma unroll
            for (int i = 0; i < 4; i++)
                #pragma unroll
                for (int j = 0; j < 2; j++)
                    acc[i][j] = __builtin_amdgcn_mfma_f32_16x16x32_bf16(af[i], bfr[j], acc[i][j], 0, 0, 0);
        }
        __syncthreads();
    }

    if constexpr (EPI == 4) {
        #pragma unroll
        for (int i = 0; i < 4; i++) {
            #pragma unroll
            for (int j = 0; j < 2; j++) {
                int row0 = m0 + wr*64 + i*16 + lg*4;
                int col = n0 + wc*32 + j*16 + l15;
                f32x4 o;
                #pragma unroll
                for (int r = 0; r < 4; r++)
                    o[r] = acc[i][j][r] + bias[col] + resid[(size_t)(row0 + r)*NT + col];
                int bb2 = row0 >= 25088;
                size_t off = (size_t)bb2*192*25088 + (size_t)col*25088 + (row0 - bb2*25088);
                *(f32x4*)&((float*)outp)[off] = o;
            }
        }
    } else {
        #pragma unroll
        for (int i = 0; i < 4; i++) {
            #pragma unroll
            for (int j = 0; j < 2; j++) {
                #pragma unroll
                for (int r = 0; r < 4; r++) {
                    int row = m0 + wr*64 + i*16 + lg*4 + r;
                    int col = n0 + wc*32 + j*16 + l15;
                    float v = acc[i][j][r] + bias[col];
                    size_t oidx = (size_t)row * NT + col;
                    if constexpr (EPI == 0) {
                        ((bf16*)outp)[oidx] = (bf16)v;
                    } else if constexpr (EPI == 1) {
                        ((float*)outp)[oidx] = v;
                    } else if constexpr (EPI == 2) {
                        float gl = 0.5f * v * (1.0f + erff(v * 0.70710678118654752f));
                        ((bf16*)outp)[oidx] = (bf16)gl;
                    }
                }
            }
        }
    }
}

// K3: attention, one block per (WINDOW, HEAD). grid 3072, block 128 (2 waves).
// Softmax additive terms come from fragment-ordered tables (one f32x4 per
// (rt,j) per lane) instead of 8 scalar gathers -> 4x fewer load instrs,
// no address math, no branches in the hot loop.
__global__ __launch_bounds__(128) void attn_k(
    const bf16* __restrict__ qkv, const float* __restrict__ biasF,
    const float* __restrict__ maskF, bf16* __restrict__ aout)
{
    __shared__ bf16 VT[32*128];      // [d][key ^ ((d&7)<<3)], keys>=98 zero
    __shared__ bf16 Pl[2*16*136];
    int blk = blockIdx.x;
    int t8 = (blk & 7) * 384 + (blk >> 3);   // XCD-contiguous task id
    int b_ = t8 / 6, head = t8 % 6;
    int tid = threadIdx.x, lane = tid & 63, wv = tid >> 6;
    int l15 = lane & 15, lg = (lane >> 4) & 3;
    int wib = b_ & 255;
    const bf16* base = qkv + (size_t)b_*98*576;

    // ---- phase 0: zero VT fully + P pad cols (112..127) ----
    {
        unsigned int* vz = (unsigned int*)VT;
        for (int e = tid; e < 2048; e += 128) vz[e] = 0u;
        unsigned int* pz = (unsigned int*)Pl;
        for (int e = tid; e < 256; e += 128) {
            int w2 = e >> 7, rem = e & 127;
            int row = rem >> 3, cp = rem & 7;
            pz[(w2*16 + row)*68 + 56 + cp] = 0u;
        }
    }
    __syncthreads();
    // ---- phase 1: stage V^T slice; k varies with lane (conflict-free) ----
    {
        int dq = tid >> 5;               // d-octet 0..3
        int kl = tid & 31;
        const bf16* vbase = base + 384 + head*32 + dq*8;
        #pragma unroll
        for (int kr = 0; kr < 4; kr++) {
            int k = kr*32 + kl;
            if (k < 98) {
                bf16x8 v8 = *(const bf16x8*)&vbase[(size_t)k*576];
                #pragma unroll
                for (int j = 0; j < 8; j++)
                    VT[(dq*8 + j)*128 + (k ^ (j << 3))] = v8[j];
            }
        }
    }
    __syncthreads();

    // ---- K fragments into registers (reused across row-tiles) ----
    bf16x8 kfr[7];
    #pragma unroll
    for (int j = 0; j < 7; j++) {
        int krow = j*16 + l15; if (krow > 97) krow = 97;   // NaN guard
        kfr[j] = *(const bf16x8*)&base[(size_t)krow*576 + 192 + head*32 + lg*8];
    }

    const float scale = 0.17677669529663687f;   // 32^-0.5
    bf16* Pw = Pl + wv*16*136;
    const int rt0 = wv ? 4 : 0, rt1 = wv ? 7 : 4;

    auto loadQ = [&](int rt) {
        int qrow = rt*16 + l15; if (qrow > 97) qrow = 97;
        return *(const bf16x8*)&base[(size_t)qrow*576 + head*32 + lg*8];
    };
    bf16x8 qf = loadQ(rt0);

    #pragma unroll 1
    for (int rt = rt0; rt < rt1; rt++) {
        bf16x8 qnext = qf;
        if (rt + 1 < rt1) qnext = loadQ(rt + 1);
        // ---- S = Q K^T ----
        f32x4 sacc[7];
        #pragma unroll
        for (int j = 0; j < 7; j++) sacc[j] = zero4();
        #pragma unroll
        for (int j = 0; j < 7; j++)
            sacc[j] = __builtin_amdgcn_mfma_f32_16x16x32_bf16(qf, kfr[j], sacc[j], 0, 0, 0);
        // ---- softmax: additive terms via fragment tables (f32x4/lane) ----
        {
            const float* bfp = biasF + ((size_t)(head*7 + rt)*7)*256 + lane*4;
            const float* mfp = maskF + ((size_t)(wib*7 + rt)*7)*256 + lane*4;
            #pragma unroll
            for (int j = 0; j < 7; j++) {
                f32x4 bv = *(const f32x4*)&bfp[j*256];
                f32x4 mv = *(const f32x4*)&mfp[j*256];
                sacc[j] = sacc[j]*scale + bv + mv;
            }
            f32x4 m4 = sacc[0];
            #pragma unroll
            for (int j = 1; j < 7; j++) {
                #pragma unroll
                for (int r = 0; r < 4; r++) m4[r] = fmaxf(m4[r], sacc[j][r]);
            }
            #pragma unroll
            for (int d = 1; d < 16; d <<= 1) {
                #pragma unroll
                for (int r = 0; r < 4; r++) m4[r] = fmaxf(m4[r], __shfl_xor(m4[r], d));
            }
            f32x4 s4 = zero4();
            #pragma unroll
            for (int j = 0; j < 7; j++) {
                #pragma unroll
                for (int r = 0; r < 4; r++) sacc[j][r] = __expf(sacc[j][r] - m4[r]);
                s4 += sacc[j];
            }
            #pragma unroll
            for (int d = 1; d < 16; d <<= 1) {
                #pragma unroll
                for (int r = 0; r < 4; r++) s4[r] += __shfl_xor(s4[r], d);
            }
            f32x4 inv4;
            #pragma unroll
            for (int r = 0; r < 4; r++) inv4[r] = 1.0f / s4[r];
            #pragma unroll
            for (int j = 0; j < 7; j++)
                #pragma unroll
                for (int r = 0; r < 4; r++)
                    Pw[(lg*4 + r)*136 + j*16 + l15] = (bf16)(sacc[j][r]*inv4[r]);
        }
        // ---- O = P V ----
        #pragma unroll
        for (int dt = 0; dt < 2; dt++) {
            int dl = dt*16 + l15;
            int xr = (dl & 7) << 3;
            f32x4 oacc = zero4();
            #pragma unroll
            for (int kc = 0; kc < 4; kc++) {
                bf16x8 pf = *(const bf16x8*)&Pw[l15*136 + kc*32 + lg*8];
                bf16x8 vf = *(const bf16x8*)&VT[dl*128 + ((kc*32 + lg*8) ^ xr)];
                oacc = __builtin_amdgcn_mfma_f32_16x16x32_bf16(pf, vf, oacc, 0, 0, 0);
            }
            #pragma unroll
            for (int r = 0; r < 4; r++) {
                int row = rt*16 + lg*4 + r;
                if (row < 98)
                    aout[((size_t)b_*98 + row)*192 + head*32 + dt*16 + l15] = (bf16)oacc[r];
            }
        }
        qf = qnext;
    }
}

// K5: window reverse + roll-back + residual(x) + LN2. grid 896.
__global__ __launch_bounds__(256) void rev_res_ln2_k(
    const float* __restrict__ x, const float* __restrict__ pw,
    const float* __restrict__ g2, const float* __restrict__ b2,
    float* __restrict__ x1, bf16* __restrict__ xn2)
{
    __shared__ float tile[56*193];
    __shared__ float mu[56], rs[56];
    int blk = blockIdx.x;
    int bb = blk / 448; int r = blk % 448; int t = r / 56; int h = r % 56;
    int ts = (t + 7) & 7;
    int hs = h - 3; if (hs < 0) hs += 56;
    int tid = threadIdx.x;
    const float* xs = x + ((size_t)bb*1536 + t)*3136 + h*56;
    for (int e = tid; e < 192*56; e += 256) {
        int c = e / 56, w = e % 56;
        tile[w*193 + c] = xs[(size_t)c*25088 + w];
    }
    __syncthreads();
    int tb = ts >> 1, wt = ts & 1, hb = hs / 7, wh = hs % 7;
    for (int e = tid; e < 56*192; e += 256) {
        int w = e / 192, c = e % 192;
        int wsp = w - 3; if (wsp < 0) wsp += 56;
        int wb = wsp / 7, ww = wsp % 7;
        size_t tok = (size_t)(bb*256 + tb*64 + hb*8 + wb)*98 + wt*49 + wh*7 + ww;
        tile[w*193 + c] += pw[tok*192 + c];
    }
    __syncthreads();
    if (tid < 224) {
        int row = tid >> 2, q = tid & 3;
        float s = 0.f, s2 = 0.f;
        for (int c = q*48; c < q*48 + 48; c++) {
            float v = tile[row*193 + c]; s += v; s2 += v*v;
        }
        s  += __shfl_xor(s, 1);  s  += __shfl_xor(s, 2);
        s2 += __shfl_xor(s2, 1); s2 += __shfl_xor(s2, 2);
        if (q == 0) {
            float m = s * (1.0f/192.0f);
            mu[row] = m;
            rs[row] = rsqrtf(s2 * (1.0f/192.0f) - m*m + 1e-5f);
        }
    }
    __syncthreads();
    size_t tok0 = ((size_t)(bb*8 + t)*56 + h)*56;
    for (int e = tid; e < 56*192; e += 256) {
        int w = e / 192, c = e % 192;
        float v = tile[w*193 + c];
        x1[(tok0 + w)*192 + c] = v;
        xn2[(tok0 + w)*192 + c] = (bf16)((v - mu[w]) * rs[w] * g2[c] + b2[c]);
    }
}

// ---------------------------------------------------------------------------
extern "C" void kernel_launch(void* const* d_in, const int* in_sizes, int n_in,
                              void* d_out, int out_size, void* d_ws, size_t ws_size,
                              hipStream_t stream)
{
    const float* x     = (const float*)d_in[0];
    const float* maskm = (const float*)d_in[1];
    const float* n1g   = (const float*)d_in[2];
    const float* n1b   = (const float*)d_in[3];
    const float* qkvw  = (const float*)d_in[4];
    const float* qkvb  = (const float*)d_in[5];
    const float* projw = (const float*)d_in[6];
    const float* projb = (const float*)d_in[7];
    const float* rpb   = (const float*)d_in[8];
    const float* n2g   = (const float*)d_in[9];
    const float* n2b   = (const float*)d_in[10];
    const float* f1w   = (const float*)d_in[11];
    const float* f1b   = (const float*)d_in[12];
    const float* f2w   = (const float*)d_in[13];
    const float* f2b   = (const float*)d_in[14];

    char* ws = (char*)d_ws;
    // weights (transposed bf16) + fragment bias table
    bf16*  qkv_wt  = (bf16*)(ws + 0);          // 221184
    bf16*  proj_wt = (bf16*)(ws + 221184);     // 73728
    bf16*  fc1_wt  = (bf16*)(ws + 294912);     // 294912
    bf16*  fc2_wt  = (bf16*)(ws + 589824);     // 294912
    float* biasF   = (float*)(ws + 884736);    // 6*7*7*64*4*4 = 294912
    // region A: xw (bf16, 19.27MB) -> reused as attn_out
    bf16* xw   = (bf16*)(ws + 1179648);
    bf16* aout = xw;
    // region B: qkv (bf16, 57.8MB) -> reused as proj-out f32
    char* Bp = ws + 1179648 + 19267584;
    bf16*  qkv  = (bf16*)Bp;
    float* pwin = (float*)Bp;
    // region C: x1 f32; region D: xn2 bf16; region E: h1 bf16
    char* Cp = Bp + 57802752;
    float* x1  = (float*)Cp;
    bf16*  xn2 = (bf16*)(Cp + 38535168);
    bf16*  h1  = (bf16*)(Cp + 38535168 + 19267584);
    // maskF (12.85MB) lives in h1's region: read only during attn,
    // clobbered later by fc1's h1 write (attn long done by then).
    float* maskF = (float*)(Cp + 38535168 + 19267584);

    prep_w_k<<<576, 256, 0, stream>>>(qkvw, projw, f1w, f2w, qkv_wt, proj_wt, fc1_wt, fc2_wt);
    prep_biasF_k<<<74, 256, 0, stream>>>(rpb, biasF);
    prep_maskF_k<<<3136, 256, 0, stream>>>(maskm, maskF);
    ln1_window_k<<<896, 256, 0, stream>>>(x, n1g, n1b, xw);
    gemm_k<192, 576, 0><<<392*9, 256, 0, stream>>>(xw, qkv_wt, qkvb, nullptr, qkv);
    attn_k<<<3072, 128, 0, stream>>>(qkv, biasF, maskF, aout);
    gemm_k<192, 192, 1><<<392*3, 256, 0, stream>>>(aout, proj_wt, projb, nullptr, pwin);
    rev_res_ln2_k<<<896, 256, 0, stream>>>(x, pwin, n2g, n2b, x1, xn2);
    gemm_k<192, 768, 2><<<392*12, 256, 0, stream>>>(xn2, fc1_wt, f1b, nullptr, h1);
    gemm_k<768, 192, 4><<<392*3, 256, 0, stream>>>(h1, fc2_wt, f2b, x1, (float*)d_out);
}